// Round 1
// baseline (391.797 us; speedup 1.0000x reference)
//
#include <hip/hip_runtime.h>

#define EPSBN 1e-5f

// ---------------------------------------------------------------------------
// K1/K6: direct 3x3 conv, 64->64 channels, pad 1, fp32.
// grid (4096/256, 64/8, B), block 256. Each thread: 1 pixel x 8 out-channels.
// ---------------------------------------------------------------------------
__global__ __launch_bounds__(256) void conv3x3_k(
    const float* __restrict__ x, const float* __restrict__ w,
    float* __restrict__ y)
{
    const int b   = blockIdx.z;
    const int cob = blockIdx.y * 8;
    const int p   = blockIdx.x * 256 + threadIdx.x;
    const int h   = p >> 6, wc = p & 63;

    float acc[8];
#pragma unroll
    for (int j = 0; j < 8; ++j) acc[j] = 0.f;

    const float* xb = x + ((size_t)b << 18);   // b * 64 * 4096

#pragma unroll
    for (int kh = 0; kh < 3; ++kh) {
#pragma unroll
        for (int kw = 0; kw < 3; ++kw) {
            const int hh = h + kh - 1, ww = wc + kw - 1;
            const bool ok = ((unsigned)hh < 64u) && ((unsigned)ww < 64u);
            const int sp = (hh << 6) + ww;
            const float* wp = w + cob * 576 + kh * 3 + kw;
            for (int ci = 0; ci < 64; ++ci) {
                const float xv = ok ? xb[(ci << 12) + sp] : 0.f;
#pragma unroll
                for (int j = 0; j < 8; ++j)
                    acc[j] += xv * wp[j * 576 + ci * 9];
            }
        }
    }

    float* yp = y + (((size_t)(b * 64 + cob)) << 12) + p;
#pragma unroll
    for (int j = 0; j < 8; ++j) yp[(size_t)j << 12] = acc[j];
}

// ---------------------------------------------------------------------------
// K2: f/g/h 1x1-conv projections (64 -> 8 each) + bias + BN (+gamma for h).
// One thread per (b, pixel). Outputs stored [B][N][8] (rows of 32B).
// ---------------------------------------------------------------------------
__global__ __launch_bounds__(256) void proj_k(
    const float* __restrict__ out1,
    const float* __restrict__ f_w, const float* __restrict__ f_b,
    const float* __restrict__ f_bw, const float* __restrict__ f_bb,
    const float* __restrict__ f_bm, const float* __restrict__ f_bv,
    const float* __restrict__ g_w, const float* __restrict__ g_b,
    const float* __restrict__ g_bw, const float* __restrict__ g_bb,
    const float* __restrict__ g_bm, const float* __restrict__ g_bv,
    const float* __restrict__ h_w, const float* __restrict__ h_b,
    const float* __restrict__ h_bw, const float* __restrict__ h_bb,
    const float* __restrict__ h_bm, const float* __restrict__ h_bv,
    const float* __restrict__ gamma,
    float* __restrict__ f, float* __restrict__ g, float* __restrict__ h)
{
    const int t = blockIdx.x * 256 + threadIdx.x;   // over B*N = 16384
    const int b = t >> 12, p = t & 4095;

    const float* xp = out1 + ((size_t)b << 18) + p;

    float aF[8], aG[8], aH[8];
#pragma unroll
    for (int c = 0; c < 8; ++c) { aF[c] = 0.f; aG[c] = 0.f; aH[c] = 0.f; }

    for (int ci = 0; ci < 64; ++ci) {
        const float xv = xp[ci << 12];
#pragma unroll
        for (int c = 0; c < 8; ++c) {
            aF[c] += xv * f_w[c * 64 + ci];
            aG[c] += xv * g_w[c * 64 + ci];
            aH[c] += xv * h_w[c * 64 + ci];
        }
    }

    const float gm = gamma[0];
    float fo[8], go[8], ho[8];
#pragma unroll
    for (int c = 0; c < 8; ++c) {
        float invf = f_bw[c] * rsqrtf(f_bv[c] + EPSBN);
        fo[c] = (aF[c] + f_b[c]) * invf + (f_bb[c] - f_bm[c] * invf);
        float invg = g_bw[c] * rsqrtf(g_bv[c] + EPSBN);
        go[c] = (aG[c] + g_b[c]) * invg + (g_bb[c] - g_bm[c] * invg);
        float invh = h_bw[c] * rsqrtf(h_bv[c] + EPSBN);
        ho[c] = gm * ((aH[c] + h_b[c]) * invh + (h_bb[c] - h_bm[c] * invh));
    }

    float4* fp = (float4*)(f + ((size_t)t << 3));
    float4* gp = (float4*)(g + ((size_t)t << 3));
    float4* hp = (float4*)(h + ((size_t)t << 3));
    fp[0] = make_float4(fo[0], fo[1], fo[2], fo[3]);
    fp[1] = make_float4(fo[4], fo[5], fo[6], fo[7]);
    gp[0] = make_float4(go[0], go[1], go[2], go[3]);
    gp[1] = make_float4(go[4], go[5], go[6], go[7]);
    hp[0] = make_float4(ho[0], ho[1], ho[2], ho[3]);
    hp[1] = make_float4(ho[4], ho[5], ho[6], ho[7]);
}

// ---------------------------------------------------------------------------
// K3 (pass 1): per-column online softmax stats.
// s[n,m] = f[n]·g[m]; M[m] = max_n s; D[m] = sum_n exp(s - M).
// Then rescale h[m][:] *= 1/D[m] in place.
// grid (N/32, B), block 256 = 32 columns x 8 n-chunks of 512.
// ---------------------------------------------------------------------------
__global__ __launch_bounds__(256) void pass1_k(
    const float* __restrict__ f, const float* __restrict__ g,
    float* __restrict__ h, float* __restrict__ Mout)
{
    __shared__ float sM[256], sD[256];

    const int b     = blockIdx.y;
    const int ml    = threadIdx.x & 31;
    const int chunk = threadIdx.x >> 5;
    const int m     = blockIdx.x * 32 + ml;

    const float4* gp = (const float4*)(g + (((size_t)(b * 4096 + m)) << 3));
    const float4 ga = gp[0], gb = gp[1];

    const float4* fp = (const float4*)(f + ((size_t)b << 15)) + (size_t)chunk * 512 * 2;

    float M = -1e30f, D = 0.f;
    for (int n = 0; n < 512; ++n) {
        const float4 fa = fp[2 * n], fb = fp[2 * n + 1];
        const float s = fa.x * ga.x + fa.y * ga.y + fa.z * ga.z + fa.w * ga.w
                      + fb.x * gb.x + fb.y * gb.y + fb.z * gb.z + fb.w * gb.w;
        if (s > M) { D = D * __expf(M - s) + 1.f; M = s; }
        else       { D += __expf(s - M); }
    }
    sM[threadIdx.x] = M;
    sD[threadIdx.x] = D;
    __syncthreads();

    if (threadIdx.x < 32) {
        float Mt = sM[threadIdx.x], Dt = sD[threadIdx.x];
#pragma unroll
        for (int i = 1; i < 8; ++i) {
            const float Mi = sM[threadIdx.x + 32 * i];
            const float Di = sD[threadIdx.x + 32 * i];
            const float Mn = fmaxf(Mt, Mi);
            Dt = Dt * __expf(Mt - Mn) + Di * __expf(Mi - Mn);
            Mt = Mn;
        }
        const int mg = blockIdx.x * 32 + threadIdx.x;
        Mout[b * 4096 + mg] = Mt;
        const float invD = 1.f / Dt;
        float4* hp = (float4*)(h + (((size_t)(b * 4096 + mg)) << 3));
        float4 ha = hp[0], hb = hp[1];
        ha.x *= invD; ha.y *= invD; ha.z *= invD; ha.w *= invD;
        hb.x *= invD; hb.y *= invD; hb.z *= invD; hb.w *= invD;
        hp[0] = ha; hp[1] = hb;
    }
}

// ---------------------------------------------------------------------------
// K4 (pass 2): o[n,c] = sum_m exp(f[n]·g[m] - M[m]) * h2[m,c]
// grid (N/32, B), block 256 = 32 rows x 8 m-chunks of 512 + LDS reduce.
// ---------------------------------------------------------------------------
__global__ __launch_bounds__(256) void pass2_k(
    const float* __restrict__ f, const float* __restrict__ g,
    const float* __restrict__ h2, const float* __restrict__ Mcol,
    float* __restrict__ o)
{
    __shared__ float sA[256][8];

    const int b     = blockIdx.y;
    const int nl    = threadIdx.x & 31;
    const int chunk = threadIdx.x >> 5;
    const int n     = blockIdx.x * 32 + nl;

    const float4* fp = (const float4*)(f + (((size_t)(b * 4096 + n)) << 3));
    const float4 fa = fp[0], fb = fp[1];

    const float4* gp = (const float4*)(g  + ((size_t)b << 15)) + (size_t)chunk * 512 * 2;
    const float4* hp = (const float4*)(h2 + ((size_t)b << 15)) + (size_t)chunk * 512 * 2;
    const float*  Mp = Mcol + b * 4096 + chunk * 512;

    float a0 = 0.f, a1 = 0.f, a2 = 0.f, a3 = 0.f;
    float a4 = 0.f, a5 = 0.f, a6 = 0.f, a7 = 0.f;

    for (int m = 0; m < 512; ++m) {
        const float4 ga = gp[2 * m], gb = gp[2 * m + 1];
        const float s = fa.x * ga.x + fa.y * ga.y + fa.z * ga.z + fa.w * ga.w
                      + fb.x * gb.x + fb.y * gb.y + fb.z * gb.z + fb.w * gb.w;
        const float e = __expf(s - Mp[m]);
        const float4 ha = hp[2 * m], hb = hp[2 * m + 1];
        a0 += e * ha.x; a1 += e * ha.y; a2 += e * ha.z; a3 += e * ha.w;
        a4 += e * hb.x; a5 += e * hb.y; a6 += e * hb.z; a7 += e * hb.w;
    }

    sA[threadIdx.x][0] = a0; sA[threadIdx.x][1] = a1;
    sA[threadIdx.x][2] = a2; sA[threadIdx.x][3] = a3;
    sA[threadIdx.x][4] = a4; sA[threadIdx.x][5] = a5;
    sA[threadIdx.x][6] = a6; sA[threadIdx.x][7] = a7;
    __syncthreads();

    const int c  = threadIdx.x & 7;
    const int mlr = threadIdx.x >> 3;      // 0..31
    float sum = 0.f;
#pragma unroll
    for (int i = 0; i < 8; ++i) sum += sA[mlr + 32 * i][c];
    o[(((size_t)(b * 4096 + blockIdx.x * 32 + mlr)) << 3) + c] = sum;
}

// ---------------------------------------------------------------------------
// K5: i 1x1-conv (8 -> 64) + bias + BN + residual with out1 -> out2.
// One thread per output element.
// ---------------------------------------------------------------------------
__global__ __launch_bounds__(256) void post_k(
    const float* __restrict__ o, const float* __restrict__ out1,
    const float* __restrict__ i_w, const float* __restrict__ i_b,
    const float* __restrict__ i_bw, const float* __restrict__ i_bb,
    const float* __restrict__ i_bm, const float* __restrict__ i_bv,
    float* __restrict__ out2)
{
    const int idx = blockIdx.x * 256 + threadIdx.x;   // over B*64*4096
    const int p  = idx & 4095;
    const int co = (idx >> 12) & 63;
    const int b  = idx >> 18;

    const float4* op = (const float4*)(o + (((size_t)(b * 4096 + p)) << 3));
    const float4 oa = op[0], ob = op[1];
    const float* wp = i_w + co * 8;

    float v = oa.x * wp[0] + oa.y * wp[1] + oa.z * wp[2] + oa.w * wp[3]
            + ob.x * wp[4] + ob.y * wp[5] + ob.z * wp[6] + ob.w * wp[7];

    const float inv = i_bw[co] * rsqrtf(i_bv[co] + EPSBN);
    out2[idx] = (v + i_b[co]) * inv + (i_bb[co] - i_bm[co] * inv) + out1[idx];
}

// ---------------------------------------------------------------------------
extern "C" void kernel_launch(void* const* d_in, const int* in_sizes, int n_in,
                              void* d_out, int out_size, void* d_ws, size_t ws_size,
                              hipStream_t stream) {
    const float* x       = (const float*)d_in[0];
    const float* conv1_w = (const float*)d_in[1];
    const float* conv2_w = (const float*)d_in[2];
    const float* f_w  = (const float*)d_in[3];
    const float* f_b  = (const float*)d_in[4];
    const float* f_bw = (const float*)d_in[5];
    const float* f_bb = (const float*)d_in[6];
    const float* f_bm = (const float*)d_in[7];
    const float* f_bv = (const float*)d_in[8];
    const float* g_w  = (const float*)d_in[9];
    const float* g_b  = (const float*)d_in[10];
    const float* g_bw = (const float*)d_in[11];
    const float* g_bb = (const float*)d_in[12];
    const float* g_bm = (const float*)d_in[13];
    const float* g_bv = (const float*)d_in[14];
    const float* gamma = (const float*)d_in[15];
    const float* h_w  = (const float*)d_in[16];
    const float* h_b  = (const float*)d_in[17];
    const float* h_bw = (const float*)d_in[18];
    const float* h_bb = (const float*)d_in[19];
    const float* h_bm = (const float*)d_in[20];
    const float* h_bv = (const float*)d_in[21];
    const float* i_w  = (const float*)d_in[22];
    const float* i_b  = (const float*)d_in[23];
    const float* i_bw = (const float*)d_in[24];
    const float* i_bb = (const float*)d_in[25];
    const float* i_bm = (const float*)d_in[26];
    const float* i_bv = (const float*)d_in[27];

    float* ws   = (float*)d_ws;
    float* out1 = ws;                 // 1,048,576 floats
    float* out2 = ws + 1048576;       // 1,048,576
    float* fbuf = ws + 2097152;       // 131,072
    float* gbuf = ws + 2228224;       // 131,072
    float* hbuf = ws + 2359296;       // 131,072
    float* Mbuf = ws + 2490368;       //  16,384
    float* obuf = ws + 2506752;       // 131,072

    // K1: conv1
    conv3x3_k<<<dim3(16, 8, 4), 256, 0, stream>>>(x, conv1_w, out1);

    // K2: f/g/h projections + BN (+gamma)
    proj_k<<<64, 256, 0, stream>>>(out1,
        f_w, f_b, f_bw, f_bb, f_bm, f_bv,
        g_w, g_b, g_bw, g_bb, g_bm, g_bv,
        h_w, h_b, h_bw, h_bb, h_bm, h_bv,
        gamma, fbuf, gbuf, hbuf);

    // K3: column softmax stats (M, D) + scale h by 1/D
    pass1_k<<<dim3(128, 4), 256, 0, stream>>>(fbuf, gbuf, hbuf, Mbuf);

    // K4: o = exp(s - M) @ h2
    pass2_k<<<dim3(128, 4), 256, 0, stream>>>(fbuf, gbuf, hbuf, Mbuf, obuf);

    // K5: i-conv + BN + residual
    post_k<<<4096, 256, 0, stream>>>(obuf, out1,
        i_w, i_b, i_bw, i_bb, i_bm, i_bv, out2);

    // K6: conv2 -> d_out
    conv3x3_k<<<dim3(16, 8, 4), 256, 0, stream>>>(out2, conv2_w, (float*)d_out);
}

// Round 2
// 292.691 us; speedup vs baseline: 1.3386x; 1.3386x over previous
//
#include <hip/hip_runtime.h>

#define EPSBN 1e-5f
#define L2E 1.44269504088896340736f

// ---------------------------------------------------------------------------
// K1/K8: direct 3x3 conv, 64->64 channels, pad 1, fp32.
// grid (4096/256, 64/8, B), block 256. Each thread: 1 pixel x 8 out-channels.
// ---------------------------------------------------------------------------
__global__ __launch_bounds__(256) void conv3x3_k(
    const float* __restrict__ x, const float* __restrict__ w,
    float* __restrict__ y)
{
    const int b   = blockIdx.z;
    const int cob = blockIdx.y * 8;
    const int p   = blockIdx.x * 256 + threadIdx.x;
    const int h   = p >> 6, wc = p & 63;

    float acc[8];
#pragma unroll
    for (int j = 0; j < 8; ++j) acc[j] = 0.f;

    const float* xb = x + ((size_t)b << 18);   // b * 64 * 4096

#pragma unroll
    for (int kh = 0; kh < 3; ++kh) {
#pragma unroll
        for (int kw = 0; kw < 3; ++kw) {
            const int hh = h + kh - 1, ww = wc + kw - 1;
            const bool ok = ((unsigned)hh < 64u) && ((unsigned)ww < 64u);
            const int sp = (hh << 6) + ww;
            const float* wp = w + cob * 576 + kh * 3 + kw;
            for (int ci = 0; ci < 64; ++ci) {
                const float xv = ok ? xb[(ci << 12) + sp] : 0.f;
#pragma unroll
                for (int j = 0; j < 8; ++j)
                    acc[j] += xv * wp[j * 576 + ci * 9];
            }
        }
    }

    float* yp = y + (((size_t)(b * 64 + cob)) << 12) + p;
#pragma unroll
    for (int j = 0; j < 8; ++j) yp[(size_t)j << 12] = acc[j];
}

// ---------------------------------------------------------------------------
// K2: f/g/h 1x1-conv projections (64 -> 8 each) + bias + BN (+gamma for h).
// f stored [B*N][8]; g,h packed interleaved gh[B*N][16] = {g[8], h[8]}.
// ---------------------------------------------------------------------------
__global__ __launch_bounds__(256) void proj_k(
    const float* __restrict__ out1,
    const float* __restrict__ f_w, const float* __restrict__ f_b,
    const float* __restrict__ f_bw, const float* __restrict__ f_bb,
    const float* __restrict__ f_bm, const float* __restrict__ f_bv,
    const float* __restrict__ g_w, const float* __restrict__ g_b,
    const float* __restrict__ g_bw, const float* __restrict__ g_bb,
    const float* __restrict__ g_bm, const float* __restrict__ g_bv,
    const float* __restrict__ h_w, const float* __restrict__ h_b,
    const float* __restrict__ h_bw, const float* __restrict__ h_bb,
    const float* __restrict__ h_bm, const float* __restrict__ h_bv,
    const float* __restrict__ gamma,
    float* __restrict__ f, float* __restrict__ gh)
{
    const int t = blockIdx.x * 256 + threadIdx.x;   // over B*N = 16384
    const int b = t >> 12, p = t & 4095;

    const float* xp = out1 + ((size_t)b << 18) + p;

    float aF[8], aG[8], aH[8];
#pragma unroll
    for (int c = 0; c < 8; ++c) { aF[c] = 0.f; aG[c] = 0.f; aH[c] = 0.f; }

    for (int ci = 0; ci < 64; ++ci) {
        const float xv = xp[ci << 12];
#pragma unroll
        for (int c = 0; c < 8; ++c) {
            aF[c] += xv * f_w[c * 64 + ci];
            aG[c] += xv * g_w[c * 64 + ci];
            aH[c] += xv * h_w[c * 64 + ci];
        }
    }

    const float gm = gamma[0];
    float fo[8], go[8], ho[8];
#pragma unroll
    for (int c = 0; c < 8; ++c) {
        float invf = f_bw[c] * rsqrtf(f_bv[c] + EPSBN);
        fo[c] = (aF[c] + f_b[c]) * invf + (f_bb[c] - f_bm[c] * invf);
        float invg = g_bw[c] * rsqrtf(g_bv[c] + EPSBN);
        go[c] = (aG[c] + g_b[c]) * invg + (g_bb[c] - g_bm[c] * invg);
        float invh = h_bw[c] * rsqrtf(h_bv[c] + EPSBN);
        ho[c] = gm * ((aH[c] + h_b[c]) * invh + (h_bb[c] - h_bm[c] * invh));
    }

    float4* fp  = (float4*)(f + ((size_t)t << 3));
    float4* ghp = (float4*)(gh + ((size_t)t << 4));
    fp[0]  = make_float4(fo[0], fo[1], fo[2], fo[3]);
    fp[1]  = make_float4(fo[4], fo[5], fo[6], fo[7]);
    ghp[0] = make_float4(go[0], go[1], go[2], go[3]);
    ghp[1] = make_float4(go[4], go[5], go[6], go[7]);
    ghp[2] = make_float4(ho[0], ho[1], ho[2], ho[3]);
    ghp[3] = make_float4(ho[4], ho[5], ho[6], ho[7]);
}

// ---------------------------------------------------------------------------
// K3: partial column softmax stats in log2 domain.
// Thread: 4 columns, n-chunk of 128 (chunk = blockIdx.y -> f loads wave-uniform
// => scalar SMEM loads). grid (4, 32, B).
// ---------------------------------------------------------------------------
__global__ __launch_bounds__(256) void pass1_k(
    const float* __restrict__ f, const float* __restrict__ gh,
    float* __restrict__ Mpart, float* __restrict__ Dpart)
{
    const int b     = blockIdx.z;
    const int chunk = blockIdx.y;                     // 0..31
    const int q     = blockIdx.x * 256 + threadIdx.x; // 0..1023
    const int c0    = q << 2;

    float g[4][8];
#pragma unroll
    for (int i = 0; i < 4; ++i) {
        const float4* gp = (const float4*)(gh + (((size_t)(b * 4096 + c0 + i)) << 4));
        const float4 ga = gp[0], gb = gp[1];
        g[i][0] = ga.x * L2E; g[i][1] = ga.y * L2E; g[i][2] = ga.z * L2E; g[i][3] = ga.w * L2E;
        g[i][4] = gb.x * L2E; g[i][5] = gb.y * L2E; g[i][6] = gb.z * L2E; g[i][7] = gb.w * L2E;
    }

    const float* fp = f + (((size_t)(b * 4096 + chunk * 128)) << 3);

    float M[4], D[4];
#pragma unroll
    for (int i = 0; i < 4; ++i) { M[i] = -1e30f; D[i] = 0.f; }

#pragma unroll 2
    for (int n = 0; n < 128; ++n) {
        const float4 fa = ((const float4*)(fp + (n << 3)))[0];
        const float4 fb = ((const float4*)(fp + (n << 3)))[1];
#pragma unroll
        for (int i = 0; i < 4; ++i) {
            float s = fa.x * g[i][0];
            s = fmaf(fa.y, g[i][1], s); s = fmaf(fa.z, g[i][2], s);
            s = fmaf(fa.w, g[i][3], s); s = fmaf(fb.x, g[i][4], s);
            s = fmaf(fb.y, g[i][5], s); s = fmaf(fb.z, g[i][6], s);
            s = fmaf(fb.w, g[i][7], s);
            const float Mn = fmaxf(M[i], s);
            const float e  = exp2f(fminf(s, M[i]) - Mn);
            D[i] = (s > M[i]) ? fmaf(D[i], e, 1.f) : (D[i] + e);
            M[i] = Mn;
        }
    }

    const size_t o = (size_t)chunk * 16384 + b * 4096 + c0;
    *(float4*)(Mpart + o) = make_float4(M[0], M[1], M[2], M[3]);
    *(float4*)(Dpart + o) = make_float4(D[0], D[1], D[2], D[3]);
}

// ---------------------------------------------------------------------------
// K4: combine 32 partial (M,D) per column; fold 2^-M / D into h half of gh.
// 16384 threads.
// ---------------------------------------------------------------------------
__global__ __launch_bounds__(256) void reduce1_k(
    const float* __restrict__ Mpart, const float* __restrict__ Dpart,
    float* __restrict__ gh)
{
    const int t = blockIdx.x * 256 + threadIdx.x;   // column id over B*N

    float M = -1e30f, D = 0.f;
    for (int ch = 0; ch < 32; ++ch) {
        const float Mp = Mpart[(size_t)ch * 16384 + t];
        const float Dp = Dpart[(size_t)ch * 16384 + t];
        const float Mn = fmaxf(M, Mp);
        D = D * exp2f(M - Mn) + Dp * exp2f(Mp - Mn);
        M = Mn;
    }
    const float scale = exp2f(-M) / D;

    float4* hp = (float4*)(gh + ((size_t)t << 4) + 8);
    float4 ha = hp[0], hb = hp[1];
    ha.x *= scale; ha.y *= scale; ha.z *= scale; ha.w *= scale;
    hb.x *= scale; hb.y *= scale; hb.z *= scale; hb.w *= scale;
    hp[0] = ha; hp[1] = hb;
}

// ---------------------------------------------------------------------------
// K5: o_partial[n,c] = sum_{m in chunk} 2^(f[n]·g[m]*L2E) * h2[m,c]
// Thread: 2 rows, m-chunk of 256 (chunk = blockIdx.y -> gh loads wave-uniform
// => scalar SMEM loads). grid (8, 16, B). Partials land in opA (8) / opB (8).
// ---------------------------------------------------------------------------
__global__ __launch_bounds__(256) void pass2_k(
    const float* __restrict__ f, const float* __restrict__ gh,
    float* __restrict__ opA, float* __restrict__ opB)
{
    const int b     = blockIdx.z;
    const int chunk = blockIdx.y;                     // 0..15
    const int q     = blockIdx.x * 256 + threadIdx.x; // 0..2047
    const int r0    = q << 1;

    float fr[2][8];
#pragma unroll
    for (int i = 0; i < 2; ++i) {
        const float4* fp = (const float4*)(f + (((size_t)(b * 4096 + r0 + i)) << 3));
        const float4 fa = fp[0], fb = fp[1];
        fr[i][0] = fa.x * L2E; fr[i][1] = fa.y * L2E; fr[i][2] = fa.z * L2E; fr[i][3] = fa.w * L2E;
        fr[i][4] = fb.x * L2E; fr[i][5] = fb.y * L2E; fr[i][6] = fb.z * L2E; fr[i][7] = fb.w * L2E;
    }

    const float* ghp = gh + (((size_t)(b * 4096 + chunk * 256)) << 4);

    float acc[2][8];
#pragma unroll
    for (int i = 0; i < 2; ++i)
#pragma unroll
        for (int j = 0; j < 8; ++j) acc[i][j] = 0.f;

#pragma unroll 2
    for (int m = 0; m < 256; ++m) {
        const float4* G = (const float4*)(ghp + ((size_t)m << 4));
        const float4 ga = G[0], gb = G[1], ha = G[2], hb = G[3];
        float e[2];
#pragma unroll
        for (int i = 0; i < 2; ++i) {
            float s = ga.x * fr[i][0];
            s = fmaf(ga.y, fr[i][1], s); s = fmaf(ga.z, fr[i][2], s);
            s = fmaf(ga.w, fr[i][3], s); s = fmaf(gb.x, fr[i][4], s);
            s = fmaf(gb.y, fr[i][5], s); s = fmaf(gb.z, fr[i][6], s);
            s = fmaf(gb.w, fr[i][7], s);
            e[i] = exp2f(s);
        }
#pragma unroll
        for (int i = 0; i < 2; ++i) {
            acc[i][0] = fmaf(e[i], ha.x, acc[i][0]);
            acc[i][1] = fmaf(e[i], ha.y, acc[i][1]);
            acc[i][2] = fmaf(e[i], ha.z, acc[i][2]);
            acc[i][3] = fmaf(e[i], ha.w, acc[i][3]);
            acc[i][4] = fmaf(e[i], hb.x, acc[i][4]);
            acc[i][5] = fmaf(e[i], hb.y, acc[i][5]);
            acc[i][6] = fmaf(e[i], hb.z, acc[i][6]);
            acc[i][7] = fmaf(e[i], hb.w, acc[i][7]);
        }
    }

    float* op = (chunk < 8) ? (opA + (size_t)chunk * 131072)
                            : (opB + (size_t)(chunk - 8) * 131072);
    float4* w = (float4*)(op + (((size_t)(b * 4096 + r0)) << 3));
    w[0] = make_float4(acc[0][0], acc[0][1], acc[0][2], acc[0][3]);
    w[1] = make_float4(acc[0][4], acc[0][5], acc[0][6], acc[0][7]);
    w[2] = make_float4(acc[1][0], acc[1][1], acc[1][2], acc[1][3]);
    w[3] = make_float4(acc[1][4], acc[1][5], acc[1][6], acc[1][7]);
}

// ---------------------------------------------------------------------------
// K6: sum 16 o-partials -> obuf[row][8]. 16384 threads.
// ---------------------------------------------------------------------------
__global__ __launch_bounds__(256) void reduce2_k(
    const float* __restrict__ opA, const float* __restrict__ opB,
    float* __restrict__ o)
{
    const int t = blockIdx.x * 256 + threadIdx.x;   // row id over B*N

    float a[8];
#pragma unroll
    for (int j = 0; j < 8; ++j) a[j] = 0.f;

#pragma unroll
    for (int ch = 0; ch < 16; ++ch) {
        const float* op = (ch < 8) ? (opA + (size_t)ch * 131072)
                                   : (opB + (size_t)(ch - 8) * 131072);
        const float4* p = (const float4*)(op + ((size_t)t << 3));
        const float4 pa = p[0], pb = p[1];
        a[0] += pa.x; a[1] += pa.y; a[2] += pa.z; a[3] += pa.w;
        a[4] += pb.x; a[5] += pb.y; a[6] += pb.z; a[7] += pb.w;
    }

    float4* w = (float4*)(o + ((size_t)t << 3));
    w[0] = make_float4(a[0], a[1], a[2], a[3]);
    w[1] = make_float4(a[4], a[5], a[6], a[7]);
}

// ---------------------------------------------------------------------------
// K7: i 1x1-conv (8 -> 64) + bias + BN + residual with out1 -> out2.
// ---------------------------------------------------------------------------
__global__ __launch_bounds__(256) void post_k(
    const float* __restrict__ o, const float* __restrict__ out1,
    const float* __restrict__ i_w, const float* __restrict__ i_b,
    const float* __restrict__ i_bw, const float* __restrict__ i_bb,
    const float* __restrict__ i_bm, const float* __restrict__ i_bv,
    float* __restrict__ out2)
{
    const int idx = blockIdx.x * 256 + threadIdx.x;   // over B*64*4096
    const int p  = idx & 4095;
    const int co = (idx >> 12) & 63;
    const int b  = idx >> 18;

    const float4* op = (const float4*)(o + (((size_t)(b * 4096 + p)) << 3));
    const float4 oa = op[0], ob = op[1];
    const float* wp = i_w + co * 8;

    float v = oa.x * wp[0] + oa.y * wp[1] + oa.z * wp[2] + oa.w * wp[3]
            + ob.x * wp[4] + ob.y * wp[5] + ob.z * wp[6] + ob.w * wp[7];

    const float inv = i_bw[co] * rsqrtf(i_bv[co] + EPSBN);
    out2[idx] = (v + i_b[co]) * inv + (i_bb[co] - i_bm[co] * inv) + out1[idx];
}

// ---------------------------------------------------------------------------
extern "C" void kernel_launch(void* const* d_in, const int* in_sizes, int n_in,
                              void* d_out, int out_size, void* d_ws, size_t ws_size,
                              hipStream_t stream) {
    const float* x       = (const float*)d_in[0];
    const float* conv1_w = (const float*)d_in[1];
    const float* conv2_w = (const float*)d_in[2];
    const float* f_w  = (const float*)d_in[3];
    const float* f_b  = (const float*)d_in[4];
    const float* f_bw = (const float*)d_in[5];
    const float* f_bb = (const float*)d_in[6];
    const float* f_bm = (const float*)d_in[7];
    const float* f_bv = (const float*)d_in[8];
    const float* g_w  = (const float*)d_in[9];
    const float* g_b  = (const float*)d_in[10];
    const float* g_bw = (const float*)d_in[11];
    const float* g_bb = (const float*)d_in[12];
    const float* g_bm = (const float*)d_in[13];
    const float* g_bv = (const float*)d_in[14];
    const float* gamma = (const float*)d_in[15];
    const float* h_w  = (const float*)d_in[16];
    const float* h_b  = (const float*)d_in[17];
    const float* h_bw = (const float*)d_in[18];
    const float* h_bb = (const float*)d_in[19];
    const float* h_bm = (const float*)d_in[20];
    const float* h_bv = (const float*)d_in[21];
    const float* i_w  = (const float*)d_in[22];
    const float* i_b  = (const float*)d_in[23];
    const float* i_bw = (const float*)d_in[24];
    const float* i_bb = (const float*)d_in[25];
    const float* i_bm = (const float*)d_in[26];
    const float* i_bv = (const float*)d_in[27];

    float* ws   = (float*)d_ws;
    float* out1 = ws;                 // 1,048,576 floats (4 MB)
    float* fbuf = ws + 1048576;       //   131,072
    float* gh   = ws + 1179648;       //   262,144
    float* obuf = ws + 1441792;       //   131,072
    float* out2 = ws + 1572864;       // 1,048,576 (4 MB) — also Mpart/Dpart/opA
    float* Mpart = out2;              //   524,288 (dead before opA used)
    float* Dpart = out2 + 524288;     //   524,288
    float* opA   = out2;              // 1,048,576 (8 chunks x 131072)
    float* opB   = (float*)d_out;     // 1,048,576 (8 chunks) — scratch until conv2

    // K1: conv1
    conv3x3_k<<<dim3(16, 8, 4), 256, 0, stream>>>(x, conv1_w, out1);

    // K2: f/g/h projections + BN (+gamma), packed gh
    proj_k<<<64, 256, 0, stream>>>(out1,
        f_w, f_b, f_bw, f_bb, f_bm, f_bv,
        g_w, g_b, g_bw, g_bb, g_bm, g_bv,
        h_w, h_b, h_bw, h_bb, h_bm, h_bv,
        gamma, fbuf, gh);

    // K3: partial column stats (32 n-chunks)
    pass1_k<<<dim3(4, 32, 4), 256, 0, stream>>>(fbuf, gh, Mpart, Dpart);

    // K4: combine stats; fold 2^-M / D into h
    reduce1_k<<<64, 256, 0, stream>>>(Mpart, Dpart, gh);

    // K5: o partials (16 m-chunks)
    pass2_k<<<dim3(8, 16, 4), 256, 0, stream>>>(fbuf, gh, opA, opB);

    // K6: sum partials
    reduce2_k<<<64, 256, 0, stream>>>(opA, opB, obuf);

    // K7: i-conv + BN + residual
    post_k<<<4096, 256, 0, stream>>>(obuf, out1,
        i_w, i_b, i_bw, i_bb, i_bm, i_bv, out2);

    // K8: conv2 -> d_out
    conv3x3_k<<<dim3(16, 8, 4), 256, 0, stream>>>(out2, conv2_w, (float*)d_out);
}

// Round 3
// 214.802 us; speedup vs baseline: 1.8240x; 1.3626x over previous
//
#include <hip/hip_runtime.h>

#define EPSBN 1e-5f
#define L2E 1.44269504088896340736f

// ---------------------------------------------------------------------------
// K1/K8: direct 3x3 conv, 64->64 ch, pad 1, fp32, LDS-staged.
// grid (16 rowbands, 8 cogroups, B), block 256.
// Block: 4 rows x 64 cols x 8 co. x staged in 2 chunks of 32 ci.
// ---------------------------------------------------------------------------
__global__ __launch_bounds__(256) void conv3x3_k(
    const float* __restrict__ x, const float* __restrict__ w,
    float* __restrict__ y)
{
    __shared__ float xs[32][6][64];   // 48 KB

    const int b   = blockIdx.z;
    const int cob = blockIdx.y * 8;
    const int r0  = blockIdx.x * 4;
    const int row = threadIdx.x >> 6;   // 0..3
    const int col = threadIdx.x & 63;

    float acc[8];
#pragma unroll
    for (int j = 0; j < 8; ++j) acc[j] = 0.f;

    const float* xb = x + ((size_t)b << 18);
    const float* wb = w + cob * 576;

    const int lane16 = threadIdx.x & 15;
    const int pair0  = threadIdx.x >> 4;   // 0..15

    for (int cc = 0; cc < 2; ++cc) {
        const int ci0 = cc << 5;

        __syncthreads();   // previous compute done before overwrite
#pragma unroll
        for (int i = 0; i < 12; ++i) {
            const int pairIdx = i * 16 + pair0;   // 0..191
            const int rt  = pairIdx >> 5;          // 0..5
            const int cil = pairIdx & 31;          // 0..31
            const int gr  = r0 - 1 + rt;
            float4 v = make_float4(0.f, 0.f, 0.f, 0.f);
            if ((unsigned)gr < 64u)
                v = *(const float4*)(xb + (((size_t)(ci0 + cil)) << 12)
                                        + (gr << 6) + (lane16 << 2));
            *(float4*)&xs[cil][rt][lane16 << 2] = v;
        }
        __syncthreads();

        for (int ci = 0; ci < 32; ++ci) {
#pragma unroll
            for (int kh = 0; kh < 3; ++kh) {
                const int rt = row + kh;
                // block-uniform weight indices -> scalar loads
                float wr[8][3];
#pragma unroll
                for (int j = 0; j < 8; ++j)
#pragma unroll
                    for (int k = 0; k < 3; ++k)
                        wr[j][k] = wb[j * 576 + (ci0 + ci) * 9 + kh * 3 + k];

                const float xm  = xs[ci][rt][col];
                const float xlv = xs[ci][rt][col - (col > 0 ? 1 : 0)];
                const float xl  = (col > 0) ? xlv : 0.f;
                const float xrv = xs[ci][rt][col + (col < 63 ? 1 : 0)];
                const float xr_ = (col < 63) ? xrv : 0.f;
#pragma unroll
                for (int j = 0; j < 8; ++j) {
                    acc[j] = fmaf(xl,  wr[j][0], acc[j]);
                    acc[j] = fmaf(xm,  wr[j][1], acc[j]);
                    acc[j] = fmaf(xr_, wr[j][2], acc[j]);
                }
            }
        }
    }

    float* yp = y + (((size_t)(b * 64 + cob)) << 12) + ((r0 + row) << 6) + col;
#pragma unroll
    for (int j = 0; j < 8; ++j) yp[(size_t)j << 12] = acc[j];
}

// ---------------------------------------------------------------------------
// K2: f/g/h 1x1-conv projections (64 -> 8 each) + bias + BN (+gamma for h).
// f stored [B*N][8]; g,h packed interleaved gh[B*N][16] = {g[8], h[8]}.
// ---------------------------------------------------------------------------
__global__ __launch_bounds__(256) void proj_k(
    const float* __restrict__ out1,
    const float* __restrict__ f_w, const float* __restrict__ f_b,
    const float* __restrict__ f_bw, const float* __restrict__ f_bb,
    const float* __restrict__ f_bm, const float* __restrict__ f_bv,
    const float* __restrict__ g_w, const float* __restrict__ g_b,
    const float* __restrict__ g_bw, const float* __restrict__ g_bb,
    const float* __restrict__ g_bm, const float* __restrict__ g_bv,
    const float* __restrict__ h_w, const float* __restrict__ h_b,
    const float* __restrict__ h_bw, const float* __restrict__ h_bb,
    const float* __restrict__ h_bm, const float* __restrict__ h_bv,
    const float* __restrict__ gamma,
    float* __restrict__ f, float* __restrict__ gh)
{
    const int t = blockIdx.x * 256 + threadIdx.x;   // over B*N = 16384
    const int b = t >> 12, p = t & 4095;

    const float* xp = out1 + ((size_t)b << 18) + p;

    float aF[8], aG[8], aH[8];
#pragma unroll
    for (int c = 0; c < 8; ++c) { aF[c] = 0.f; aG[c] = 0.f; aH[c] = 0.f; }

    for (int ci = 0; ci < 64; ++ci) {
        const float xv = xp[ci << 12];
#pragma unroll
        for (int c = 0; c < 8; ++c) {
            aF[c] += xv * f_w[c * 64 + ci];
            aG[c] += xv * g_w[c * 64 + ci];
            aH[c] += xv * h_w[c * 64 + ci];
        }
    }

    const float gm = gamma[0];
    float fo[8], go[8], ho[8];
#pragma unroll
    for (int c = 0; c < 8; ++c) {
        float invf = f_bw[c] * rsqrtf(f_bv[c] + EPSBN);
        fo[c] = (aF[c] + f_b[c]) * invf + (f_bb[c] - f_bm[c] * invf);
        float invg = g_bw[c] * rsqrtf(g_bv[c] + EPSBN);
        go[c] = (aG[c] + g_b[c]) * invg + (g_bb[c] - g_bm[c] * invg);
        float invh = h_bw[c] * rsqrtf(h_bv[c] + EPSBN);
        ho[c] = gm * ((aH[c] + h_b[c]) * invh + (h_bb[c] - h_bm[c] * invh));
    }

    float4* fp  = (float4*)(f + ((size_t)t << 3));
    float4* ghp = (float4*)(gh + ((size_t)t << 4));
    fp[0]  = make_float4(fo[0], fo[1], fo[2], fo[3]);
    fp[1]  = make_float4(fo[4], fo[5], fo[6], fo[7]);
    ghp[0] = make_float4(go[0], go[1], go[2], go[3]);
    ghp[1] = make_float4(go[4], go[5], go[6], go[7]);
    ghp[2] = make_float4(ho[0], ho[1], ho[2], ho[3]);
    ghp[3] = make_float4(ho[4], ho[5], ho[6], ho[7]);
}

// ---------------------------------------------------------------------------
// K3: partial column softmax stats in log2 domain.
// Thread: 4 columns, n-chunk of 128 (chunk = blockIdx.y -> f loads wave-uniform
// => scalar SMEM loads). grid (4, 32, B).
// ---------------------------------------------------------------------------
__global__ __launch_bounds__(256) void pass1_k(
    const float* __restrict__ f, const float* __restrict__ gh,
    float* __restrict__ Mpart, float* __restrict__ Dpart)
{
    const int b     = blockIdx.z;
    const int chunk = blockIdx.y;                     // 0..31
    const int q     = blockIdx.x * 256 + threadIdx.x; // 0..1023
    const int c0    = q << 2;

    float g[4][8];
#pragma unroll
    for (int i = 0; i < 4; ++i) {
        const float4* gp = (const float4*)(gh + (((size_t)(b * 4096 + c0 + i)) << 4));
        const float4 ga = gp[0], gb = gp[1];
        g[i][0] = ga.x * L2E; g[i][1] = ga.y * L2E; g[i][2] = ga.z * L2E; g[i][3] = ga.w * L2E;
        g[i][4] = gb.x * L2E; g[i][5] = gb.y * L2E; g[i][6] = gb.z * L2E; g[i][7] = gb.w * L2E;
    }

    const float* fp = f + (((size_t)(b * 4096 + chunk * 128)) << 3);

    float M[4], D[4];
#pragma unroll
    for (int i = 0; i < 4; ++i) { M[i] = -1e30f; D[i] = 0.f; }

#pragma unroll 2
    for (int n = 0; n < 128; ++n) {
        const float4 fa = ((const float4*)(fp + (n << 3)))[0];
        const float4 fb = ((const float4*)(fp + (n << 3)))[1];
#pragma unroll
        for (int i = 0; i < 4; ++i) {
            float s = fa.x * g[i][0];
            s = fmaf(fa.y, g[i][1], s); s = fmaf(fa.z, g[i][2], s);
            s = fmaf(fa.w, g[i][3], s); s = fmaf(fb.x, g[i][4], s);
            s = fmaf(fb.y, g[i][5], s); s = fmaf(fb.z, g[i][6], s);
            s = fmaf(fb.w, g[i][7], s);
            const float Mn = fmaxf(M[i], s);
            const float e  = exp2f(fminf(s, M[i]) - Mn);
            D[i] = (s > M[i]) ? fmaf(D[i], e, 1.f) : (D[i] + e);
            M[i] = Mn;
        }
    }

    const size_t o = (size_t)chunk * 16384 + b * 4096 + c0;
    *(float4*)(Mpart + o) = make_float4(M[0], M[1], M[2], M[3]);
    *(float4*)(Dpart + o) = make_float4(D[0], D[1], D[2], D[3]);
}

// ---------------------------------------------------------------------------
// K4: combine 32 partial (M,D) per column; fold 2^-M / D into h half of gh.
// 16384 threads.
// ---------------------------------------------------------------------------
__global__ __launch_bounds__(256) void reduce1_k(
    const float* __restrict__ Mpart, const float* __restrict__ Dpart,
    float* __restrict__ gh)
{
    const int t = blockIdx.x * 256 + threadIdx.x;   // column id over B*N

    float M = -1e30f, D = 0.f;
    for (int ch = 0; ch < 32; ++ch) {
        const float Mp = Mpart[(size_t)ch * 16384 + t];
        const float Dp = Dpart[(size_t)ch * 16384 + t];
        const float Mn = fmaxf(M, Mp);
        D = D * exp2f(M - Mn) + Dp * exp2f(Mp - Mn);
        M = Mn;
    }
    const float scale = exp2f(-M) / D;

    float4* hp = (float4*)(gh + ((size_t)t << 4) + 8);
    float4 ha = hp[0], hb = hp[1];
    ha.x *= scale; ha.y *= scale; ha.z *= scale; ha.w *= scale;
    hb.x *= scale; hb.y *= scale; hb.z *= scale; hb.w *= scale;
    hp[0] = ha; hp[1] = hb;
}

// ---------------------------------------------------------------------------
// K5: o_partial[n,c] = sum_{m in chunk} 2^(f[n]·g[m]*L2E) * h2[m,c]
// Thread: 2 rows, m-chunk of 256 (chunk = blockIdx.y -> gh loads wave-uniform
// => scalar SMEM loads). grid (8, 16, B). Partials land in opA (8) / opB (8).
// ---------------------------------------------------------------------------
__global__ __launch_bounds__(256) void pass2_k(
    const float* __restrict__ f, const float* __restrict__ gh,
    float* __restrict__ opA, float* __restrict__ opB)
{
    const int b     = blockIdx.z;
    const int chunk = blockIdx.y;                     // 0..15
    const int q     = blockIdx.x * 256 + threadIdx.x; // 0..2047
    const int r0    = q << 1;

    float fr[2][8];
#pragma unroll
    for (int i = 0; i < 2; ++i) {
        const float4* fp = (const float4*)(f + (((size_t)(b * 4096 + r0 + i)) << 3));
        const float4 fa = fp[0], fb = fp[1];
        fr[i][0] = fa.x * L2E; fr[i][1] = fa.y * L2E; fr[i][2] = fa.z * L2E; fr[i][3] = fa.w * L2E;
        fr[i][4] = fb.x * L2E; fr[i][5] = fb.y * L2E; fr[i][6] = fb.z * L2E; fr[i][7] = fb.w * L2E;
    }

    const float* ghp = gh + (((size_t)(b * 4096 + chunk * 256)) << 4);

    float acc[2][8];
#pragma unroll
    for (int i = 0; i < 2; ++i)
#pragma unroll
        for (int j = 0; j < 8; ++j) acc[i][j] = 0.f;

#pragma unroll 2
    for (int m = 0; m < 256; ++m) {
        const float4* G = (const float4*)(ghp + ((size_t)m << 4));
        const float4 ga = G[0], gb = G[1], ha = G[2], hb = G[3];
        float e[2];
#pragma unroll
        for (int i = 0; i < 2; ++i) {
            float s = ga.x * fr[i][0];
            s = fmaf(ga.y, fr[i][1], s); s = fmaf(ga.z, fr[i][2], s);
            s = fmaf(ga.w, fr[i][3], s); s = fmaf(gb.x, fr[i][4], s);
            s = fmaf(gb.y, fr[i][5], s); s = fmaf(gb.z, fr[i][6], s);
            s = fmaf(gb.w, fr[i][7], s);
            e[i] = exp2f(s);
        }
#pragma unroll
        for (int i = 0; i < 2; ++i) {
            acc[i][0] = fmaf(e[i], ha.x, acc[i][0]);
            acc[i][1] = fmaf(e[i], ha.y, acc[i][1]);
            acc[i][2] = fmaf(e[i], ha.z, acc[i][2]);
            acc[i][3] = fmaf(e[i], ha.w, acc[i][3]);
            acc[i][4] = fmaf(e[i], hb.x, acc[i][4]);
            acc[i][5] = fmaf(e[i], hb.y, acc[i][5]);
            acc[i][6] = fmaf(e[i], hb.z, acc[i][6]);
            acc[i][7] = fmaf(e[i], hb.w, acc[i][7]);
        }
    }

    float* op = (chunk < 8) ? (opA + (size_t)chunk * 131072)
                            : (opB + (size_t)(chunk - 8) * 131072);
    float4* wv = (float4*)(op + (((size_t)(b * 4096 + r0)) << 3));
    wv[0] = make_float4(acc[0][0], acc[0][1], acc[0][2], acc[0][3]);
    wv[1] = make_float4(acc[0][4], acc[0][5], acc[0][6], acc[0][7]);
    wv[2] = make_float4(acc[1][0], acc[1][1], acc[1][2], acc[1][3]);
    wv[3] = make_float4(acc[1][4], acc[1][5], acc[1][6], acc[1][7]);
}

// ---------------------------------------------------------------------------
// K6: sum 16 o-partials -> obuf[row][8]. 16384 threads.
// ---------------------------------------------------------------------------
__global__ __launch_bounds__(256) void reduce2_k(
    const float* __restrict__ opA, const float* __restrict__ opB,
    float* __restrict__ o)
{
    const int t = blockIdx.x * 256 + threadIdx.x;   // row id over B*N

    float a[8];
#pragma unroll
    for (int j = 0; j < 8; ++j) a[j] = 0.f;

#pragma unroll
    for (int ch = 0; ch < 16; ++ch) {
        const float* op = (ch < 8) ? (opA + (size_t)ch * 131072)
                                   : (opB + (size_t)(ch - 8) * 131072);
        const float4* p = (const float4*)(op + ((size_t)t << 3));
        const float4 pa = p[0], pb = p[1];
        a[0] += pa.x; a[1] += pa.y; a[2] += pa.z; a[3] += pa.w;
        a[4] += pb.x; a[5] += pb.y; a[6] += pb.z; a[7] += pb.w;
    }

    float4* wv = (float4*)(o + ((size_t)t << 3));
    wv[0] = make_float4(a[0], a[1], a[2], a[3]);
    wv[1] = make_float4(a[4], a[5], a[6], a[7]);
}

// ---------------------------------------------------------------------------
// K7: i 1x1-conv (8 -> 64) + bias + BN + residual with out1 -> out2.
// ---------------------------------------------------------------------------
__global__ __launch_bounds__(256) void post_k(
    const float* __restrict__ o, const float* __restrict__ out1,
    const float* __restrict__ i_w, const float* __restrict__ i_b,
    const float* __restrict__ i_bw, const float* __restrict__ i_bb,
    const float* __restrict__ i_bm, const float* __restrict__ i_bv,
    float* __restrict__ out2)
{
    const int idx = blockIdx.x * 256 + threadIdx.x;   // over B*64*4096
    const int p  = idx & 4095;
    const int co = (idx >> 12) & 63;
    const int b  = idx >> 18;

    const float4* op = (const float4*)(o + (((size_t)(b * 4096 + p)) << 3));
    const float4 oa = op[0], ob = op[1];
    const float* wp = i_w + co * 8;

    float v = oa.x * wp[0] + oa.y * wp[1] + oa.z * wp[2] + oa.w * wp[3]
            + ob.x * wp[4] + ob.y * wp[5] + ob.z * wp[6] + ob.w * wp[7];

    const float inv = i_bw[co] * rsqrtf(i_bv[co] + EPSBN);
    out2[idx] = (v + i_b[co]) * inv + (i_bb[co] - i_bm[co] * inv) + out1[idx];
}

// ---------------------------------------------------------------------------
extern "C" void kernel_launch(void* const* d_in, const int* in_sizes, int n_in,
                              void* d_out, int out_size, void* d_ws, size_t ws_size,
                              hipStream_t stream) {
    const float* x       = (const float*)d_in[0];
    const float* conv1_w = (const float*)d_in[1];
    const float* conv2_w = (const float*)d_in[2];
    const float* f_w  = (const float*)d_in[3];
    const float* f_b  = (const float*)d_in[4];
    const float* f_bw = (const float*)d_in[5];
    const float* f_bb = (const float*)d_in[6];
    const float* f_bm = (const float*)d_in[7];
    const float* f_bv = (const float*)d_in[8];
    const float* g_w  = (const float*)d_in[9];
    const float* g_b  = (const float*)d_in[10];
    const float* g_bw = (const float*)d_in[11];
    const float* g_bb = (const float*)d_in[12];
    const float* g_bm = (const float*)d_in[13];
    const float* g_bv = (const float*)d_in[14];
    const float* gamma = (const float*)d_in[15];
    const float* h_w  = (const float*)d_in[16];
    const float* h_b  = (const float*)d_in[17];
    const float* h_bw = (const float*)d_in[18];
    const float* h_bb = (const float*)d_in[19];
    const float* h_bm = (const float*)d_in[20];
    const float* h_bv = (const float*)d_in[21];
    const float* i_w  = (const float*)d_in[22];
    const float* i_b  = (const float*)d_in[23];
    const float* i_bw = (const float*)d_in[24];
    const float* i_bb = (const float*)d_in[25];
    const float* i_bm = (const float*)d_in[26];
    const float* i_bv = (const float*)d_in[27];

    float* ws   = (float*)d_ws;
    float* out1 = ws;                 // 1,048,576 floats (4 MB)
    float* fbuf = ws + 1048576;       //   131,072
    float* gh   = ws + 1179648;       //   262,144
    float* obuf = ws + 1441792;       //   131,072
    float* out2 = ws + 1572864;       // 1,048,576 (4 MB) — also Mpart/Dpart/opA
    float* Mpart = out2;              //   524,288 (dead before opA used)
    float* Dpart = out2 + 524288;     //   524,288
    float* opA   = out2;              // 1,048,576 (8 chunks x 131072)
    float* opB   = (float*)d_out;     // 1,048,576 (8 chunks) — scratch until conv2

    // K1: conv1
    conv3x3_k<<<dim3(16, 8, 4), 256, 0, stream>>>(x, conv1_w, out1);

    // K2: f/g/h projections + BN (+gamma), packed gh
    proj_k<<<64, 256, 0, stream>>>(out1,
        f_w, f_b, f_bw, f_bb, f_bm, f_bv,
        g_w, g_b, g_bw, g_bb, g_bm, g_bv,
        h_w, h_b, h_bw, h_bb, h_bm, h_bv,
        gamma, fbuf, gh);

    // K3: partial column stats (32 n-chunks)
    pass1_k<<<dim3(4, 32, 4), 256, 0, stream>>>(fbuf, gh, Mpart, Dpart);

    // K4: combine stats; fold 2^-M / D into h
    reduce1_k<<<64, 256, 0, stream>>>(Mpart, Dpart, gh);

    // K5: o partials (16 m-chunks)
    pass2_k<<<dim3(8, 16, 4), 256, 0, stream>>>(fbuf, gh, opA, opB);

    // K6: sum partials
    reduce2_k<<<64, 256, 0, stream>>>(opA, opB, obuf);

    // K7: i-conv + BN + residual
    post_k<<<4096, 256, 0, stream>>>(obuf, out1,
        i_w, i_b, i_bw, i_bb, i_bm, i_bv, out2);

    // K8: conv2 -> d_out
    conv3x3_k<<<dim3(16, 8, 4), 256, 0, stream>>>(out2, conv2_w, (float*)d_out);
}

// Round 4
// 197.995 us; speedup vs baseline: 1.9788x; 1.0849x over previous
//
#include <hip/hip_runtime.h>

#define EPSBN 1e-5f
#define L2E 1.44269504088896340736f

// ---------------------------------------------------------------------------
// K1/K8: direct 3x3 conv, 64->64 ch, pad 1, fp32, LDS-staged.
// grid (16 rowbands, 8 cogroups, B), block 256.
// Block: 4 rows x 64 cols x 8 co. x staged in 2 chunks of 32 ci.
// ---------------------------------------------------------------------------
__global__ __launch_bounds__(256) void conv3x3_k(
    const float* __restrict__ x, const float* __restrict__ w,
    float* __restrict__ y)
{
    __shared__ float xs[32][6][64];   // 48 KB

    const int b   = blockIdx.z;
    const int cob = blockIdx.y * 8;
    const int r0  = blockIdx.x * 4;
    const int row = threadIdx.x >> 6;   // 0..3
    const int col = threadIdx.x & 63;

    float acc[8];
#pragma unroll
    for (int j = 0; j < 8; ++j) acc[j] = 0.f;

    const float* xb = x + ((size_t)b << 18);
    const float* wb = w + cob * 576;

    const int lane16 = threadIdx.x & 15;
    const int pair0  = threadIdx.x >> 4;   // 0..15

    for (int cc = 0; cc < 2; ++cc) {
        const int ci0 = cc << 5;

        __syncthreads();   // previous compute done before overwrite
#pragma unroll
        for (int i = 0; i < 12; ++i) {
            const int pairIdx = i * 16 + pair0;   // 0..191
            const int rt  = pairIdx >> 5;          // 0..5
            const int cil = pairIdx & 31;          // 0..31
            const int gr  = r0 - 1 + rt;
            float4 v = make_float4(0.f, 0.f, 0.f, 0.f);
            if ((unsigned)gr < 64u)
                v = *(const float4*)(xb + (((size_t)(ci0 + cil)) << 12)
                                        + (gr << 6) + (lane16 << 2));
            *(float4*)&xs[cil][rt][lane16 << 2] = v;
        }
        __syncthreads();

        for (int ci = 0; ci < 32; ++ci) {
#pragma unroll
            for (int kh = 0; kh < 3; ++kh) {
                const int rt = row + kh;
                // block-uniform weight indices -> scalar loads
                float wr[8][3];
#pragma unroll
                for (int j = 0; j < 8; ++j)
#pragma unroll
                    for (int k = 0; k < 3; ++k)
                        wr[j][k] = wb[j * 576 + (ci0 + ci) * 9 + kh * 3 + k];

                const float xm  = xs[ci][rt][col];
                const float xlv = xs[ci][rt][col - (col > 0 ? 1 : 0)];
                const float xl  = (col > 0) ? xlv : 0.f;
                const float xrv = xs[ci][rt][col + (col < 63 ? 1 : 0)];
                const float xr_ = (col < 63) ? xrv : 0.f;
#pragma unroll
                for (int j = 0; j < 8; ++j) {
                    acc[j] = fmaf(xl,  wr[j][0], acc[j]);
                    acc[j] = fmaf(xm,  wr[j][1], acc[j]);
                    acc[j] = fmaf(xr_, wr[j][2], acc[j]);
                }
            }
        }
    }

    float* yp = y + (((size_t)(b * 64 + cob)) << 12) + ((r0 + row) << 6) + col;
#pragma unroll
    for (int j = 0; j < 8; ++j) yp[(size_t)j << 12] = acc[j];
}

// ---------------------------------------------------------------------------
// K2: f/g/h 1x1-conv projections (64 -> 8 each) + bias + BN (+gamma for h).
// f stored [B*N][8] PRE-SCALED by L2E; g,h packed gh[B*N][16] = {g[8], h[8]}.
// block 64, grid 256 (spread over all CUs).
// ---------------------------------------------------------------------------
__global__ __launch_bounds__(64) void proj_k(
    const float* __restrict__ out1,
    const float* __restrict__ f_w, const float* __restrict__ f_b,
    const float* __restrict__ f_bw, const float* __restrict__ f_bb,
    const float* __restrict__ f_bm, const float* __restrict__ f_bv,
    const float* __restrict__ g_w, const float* __restrict__ g_b,
    const float* __restrict__ g_bw, const float* __restrict__ g_bb,
    const float* __restrict__ g_bm, const float* __restrict__ g_bv,
    const float* __restrict__ h_w, const float* __restrict__ h_b,
    const float* __restrict__ h_bw, const float* __restrict__ h_bb,
    const float* __restrict__ h_bm, const float* __restrict__ h_bv,
    const float* __restrict__ gamma,
    float* __restrict__ f, float* __restrict__ gh)
{
    const int t = blockIdx.x * 64 + threadIdx.x;   // over B*N = 16384
    const int b = t >> 12, p = t & 4095;

    const float* xp = out1 + ((size_t)b << 18) + p;

    float aF[8], aG[8], aH[8];
#pragma unroll
    for (int c = 0; c < 8; ++c) { aF[c] = 0.f; aG[c] = 0.f; aH[c] = 0.f; }

    for (int ci = 0; ci < 64; ++ci) {
        const float xv = xp[ci << 12];
#pragma unroll
        for (int c = 0; c < 8; ++c) {
            aF[c] += xv * f_w[c * 64 + ci];
            aG[c] += xv * g_w[c * 64 + ci];
            aH[c] += xv * h_w[c * 64 + ci];
        }
    }

    const float gm = gamma[0];
    float fo[8], go[8], ho[8];
#pragma unroll
    for (int c = 0; c < 8; ++c) {
        float invf = f_bw[c] * rsqrtf(f_bv[c] + EPSBN);
        fo[c] = ((aF[c] + f_b[c]) * invf + (f_bb[c] - f_bm[c] * invf)) * L2E;
        float invg = g_bw[c] * rsqrtf(g_bv[c] + EPSBN);
        go[c] = (aG[c] + g_b[c]) * invg + (g_bb[c] - g_bm[c] * invg);
        float invh = h_bw[c] * rsqrtf(h_bv[c] + EPSBN);
        ho[c] = gm * ((aH[c] + h_b[c]) * invh + (h_bb[c] - h_bm[c] * invh));
    }

    float4* fp  = (float4*)(f + ((size_t)t << 3));
    float4* ghp = (float4*)(gh + ((size_t)t << 4));
    fp[0]  = make_float4(fo[0], fo[1], fo[2], fo[3]);
    fp[1]  = make_float4(fo[4], fo[5], fo[6], fo[7]);
    ghp[0] = make_float4(go[0], go[1], go[2], go[3]);
    ghp[1] = make_float4(go[4], go[5], go[6], go[7]);
    ghp[2] = make_float4(ho[0], ho[1], ho[2], ho[3]);
    ghp[3] = make_float4(ho[4], ho[5], ho[6], ho[7]);
}

// ---------------------------------------------------------------------------
// K3: partial column softmax stats in log2 domain (f carries L2E).
// Thread: 2 columns, n-chunk of 128 (chunk = blockIdx.y -> f loads
// wave-uniform => scalar SMEM loads). grid (8, 32, B) = 1024 blocks.
// ---------------------------------------------------------------------------
__global__ __launch_bounds__(256) void pass1_k(
    const float* __restrict__ f, const float* __restrict__ gh,
    float* __restrict__ Mpart, float* __restrict__ Dpart)
{
    const int b     = blockIdx.z;
    const int chunk = blockIdx.y;                     // 0..31
    const int q     = blockIdx.x * 256 + threadIdx.x; // 0..2047
    const int c0    = q << 1;

    float g0[8], g1[8];
    {
        const float4* gp = (const float4*)(gh + (((size_t)(b * 4096 + c0)) << 4));
        const float4 a0 = gp[0], b0 = gp[1];
        const float4 a1 = gp[4], b1 = gp[5];
        g0[0]=a0.x; g0[1]=a0.y; g0[2]=a0.z; g0[3]=a0.w;
        g0[4]=b0.x; g0[5]=b0.y; g0[6]=b0.z; g0[7]=b0.w;
        g1[0]=a1.x; g1[1]=a1.y; g1[2]=a1.z; g1[3]=a1.w;
        g1[4]=b1.x; g1[5]=b1.y; g1[6]=b1.z; g1[7]=b1.w;
    }

    const float* fp = f + (((size_t)(b * 4096 + chunk * 128)) << 3);

    float M0 = -1e30f, D0 = 0.f, M1 = -1e30f, D1 = 0.f;

#pragma unroll 4
    for (int n = 0; n < 128; ++n) {
        const float4 fa = ((const float4*)(fp + (n << 3)))[0];
        const float4 fb = ((const float4*)(fp + (n << 3)))[1];
        float s0 = fa.x * g0[0];
        s0 = fmaf(fa.y, g0[1], s0); s0 = fmaf(fa.z, g0[2], s0);
        s0 = fmaf(fa.w, g0[3], s0); s0 = fmaf(fb.x, g0[4], s0);
        s0 = fmaf(fb.y, g0[5], s0); s0 = fmaf(fb.z, g0[6], s0);
        s0 = fmaf(fb.w, g0[7], s0);
        float s1 = fa.x * g1[0];
        s1 = fmaf(fa.y, g1[1], s1); s1 = fmaf(fa.z, g1[2], s1);
        s1 = fmaf(fa.w, g1[3], s1); s1 = fmaf(fb.x, g1[4], s1);
        s1 = fmaf(fb.y, g1[5], s1); s1 = fmaf(fb.z, g1[6], s1);
        s1 = fmaf(fb.w, g1[7], s1);
        {
            const float Mn = fmaxf(M0, s0);
            const float e  = exp2f(fminf(s0, M0) - Mn);
            D0 = (s0 > M0) ? fmaf(D0, e, 1.f) : (D0 + e);
            M0 = Mn;
        }
        {
            const float Mn = fmaxf(M1, s1);
            const float e  = exp2f(fminf(s1, M1) - Mn);
            D1 = (s1 > M1) ? fmaf(D1, e, 1.f) : (D1 + e);
            M1 = Mn;
        }
    }

    const size_t o = (size_t)chunk * 16384 + b * 4096 + c0;
    *(float2*)(Mpart + o) = make_float2(M0, M1);
    *(float2*)(Dpart + o) = make_float2(D0, D1);
}

// ---------------------------------------------------------------------------
// K4: combine 32 partial (M,D) per column; fold 2^-M / D into h half of gh.
// block 64, grid 256.
// ---------------------------------------------------------------------------
__global__ __launch_bounds__(64) void reduce1_k(
    const float* __restrict__ Mpart, const float* __restrict__ Dpart,
    float* __restrict__ gh)
{
    const int t = blockIdx.x * 64 + threadIdx.x;   // column id over B*N

    float M = -1e30f, D = 0.f;
#pragma unroll 8
    for (int ch = 0; ch < 32; ++ch) {
        const float Mp = Mpart[(size_t)ch * 16384 + t];
        const float Dp = Dpart[(size_t)ch * 16384 + t];
        const float Mn = fmaxf(M, Mp);
        D = D * exp2f(M - Mn) + Dp * exp2f(Mp - Mn);
        M = Mn;
    }
    const float scale = exp2f(-M) / D;

    float4* hp = (float4*)(gh + ((size_t)t << 4) + 8);
    float4 ha = hp[0], hb = hp[1];
    ha.x *= scale; ha.y *= scale; ha.z *= scale; ha.w *= scale;
    hb.x *= scale; hb.y *= scale; hb.z *= scale; hb.w *= scale;
    hp[0] = ha; hp[1] = hb;
}

// ---------------------------------------------------------------------------
// K5: o_partial[n,c] = sum_{m in chunk} 2^(f[n]·g[m]) * h2[m,c]
// Thread: 1 row, m-chunk of 256 (chunk = blockIdx.y -> gh loads wave-uniform
// => scalar SMEM loads). grid (16, 16, B) = 1024 blocks.
// ---------------------------------------------------------------------------
__global__ __launch_bounds__(256) void pass2_k(
    const float* __restrict__ f, const float* __restrict__ gh,
    float* __restrict__ opA, float* __restrict__ opB)
{
    const int b     = blockIdx.z;
    const int chunk = blockIdx.y;                     // 0..15
    const int r     = blockIdx.x * 256 + threadIdx.x; // 0..4095

    float fr[8];
    {
        const float4* fp = (const float4*)(f + (((size_t)(b * 4096 + r)) << 3));
        const float4 fa = fp[0], fb = fp[1];
        fr[0] = fa.x; fr[1] = fa.y; fr[2] = fa.z; fr[3] = fa.w;
        fr[4] = fb.x; fr[5] = fb.y; fr[6] = fb.z; fr[7] = fb.w;
    }

    const float* ghp = gh + (((size_t)(b * 4096 + chunk * 256)) << 4);

    float a0 = 0.f, a1 = 0.f, a2 = 0.f, a3 = 0.f;
    float a4 = 0.f, a5 = 0.f, a6 = 0.f, a7 = 0.f;

#pragma unroll 4
    for (int m = 0; m < 256; ++m) {
        const float4* G = (const float4*)(ghp + ((size_t)m << 4));
        const float4 ga = G[0], gb = G[1], ha = G[2], hb = G[3];
        float s = ga.x * fr[0];
        s = fmaf(ga.y, fr[1], s); s = fmaf(ga.z, fr[2], s);
        s = fmaf(ga.w, fr[3], s); s = fmaf(gb.x, fr[4], s);
        s = fmaf(gb.y, fr[5], s); s = fmaf(gb.z, fr[6], s);
        s = fmaf(gb.w, fr[7], s);
        const float e = exp2f(s);
        a0 = fmaf(e, ha.x, a0); a1 = fmaf(e, ha.y, a1);
        a2 = fmaf(e, ha.z, a2); a3 = fmaf(e, ha.w, a3);
        a4 = fmaf(e, hb.x, a4); a5 = fmaf(e, hb.y, a5);
        a6 = fmaf(e, hb.z, a6); a7 = fmaf(e, hb.w, a7);
    }

    float* op = (chunk < 8) ? (opA + (size_t)chunk * 131072)
                            : (opB + (size_t)(chunk - 8) * 131072);
    float4* wv = (float4*)(op + (((size_t)(b * 4096 + r)) << 3));
    wv[0] = make_float4(a0, a1, a2, a3);
    wv[1] = make_float4(a4, a5, a6, a7);
}

// ---------------------------------------------------------------------------
// K6: sum 16 o-partials -> obuf[row][8]. block 64, grid 256.
// ---------------------------------------------------------------------------
__global__ __launch_bounds__(64) void reduce2_k(
    const float* __restrict__ opA, const float* __restrict__ opB,
    float* __restrict__ o)
{
    const int t = blockIdx.x * 64 + threadIdx.x;   // row id over B*N

    float a[8];
#pragma unroll
    for (int j = 0; j < 8; ++j) a[j] = 0.f;

#pragma unroll
    for (int ch = 0; ch < 16; ++ch) {
        const float* op = (ch < 8) ? (opA + (size_t)ch * 131072)
                                   : (opB + (size_t)(ch - 8) * 131072);
        const float4* p = (const float4*)(op + ((size_t)t << 3));
        const float4 pa = p[0], pb = p[1];
        a[0] += pa.x; a[1] += pa.y; a[2] += pa.z; a[3] += pa.w;
        a[4] += pb.x; a[5] += pb.y; a[6] += pb.z; a[7] += pb.w;
    }

    float4* wv = (float4*)(o + ((size_t)t << 3));
    wv[0] = make_float4(a[0], a[1], a[2], a[3]);
    wv[1] = make_float4(a[4], a[5], a[6], a[7]);
}

// ---------------------------------------------------------------------------
// K7: i 1x1-conv (8 -> 64) + bias + BN + residual with out1 -> out2.
// ---------------------------------------------------------------------------
__global__ __launch_bounds__(256) void post_k(
    const float* __restrict__ o, const float* __restrict__ out1,
    const float* __restrict__ i_w, const float* __restrict__ i_b,
    const float* __restrict__ i_bw, const float* __restrict__ i_bb,
    const float* __restrict__ i_bm, const float* __restrict__ i_bv,
    float* __restrict__ out2)
{
    const int idx = blockIdx.x * 256 + threadIdx.x;   // over B*64*4096
    const int p  = idx & 4095;
    const int co = (idx >> 12) & 63;
    const int b  = idx >> 18;

    const float4* op = (const float4*)(o + (((size_t)(b * 4096 + p)) << 3));
    const float4 oa = op[0], ob = op[1];
    const float* wp = i_w + co * 8;

    float v = oa.x * wp[0] + oa.y * wp[1] + oa.z * wp[2] + oa.w * wp[3]
            + ob.x * wp[4] + ob.y * wp[5] + ob.z * wp[6] + ob.w * wp[7];

    const float inv = i_bw[co] * rsqrtf(i_bv[co] + EPSBN);
    out2[idx] = (v + i_b[co]) * inv + (i_bb[co] - i_bm[co] * inv) + out1[idx];
}

// ---------------------------------------------------------------------------
extern "C" void kernel_launch(void* const* d_in, const int* in_sizes, int n_in,
                              void* d_out, int out_size, void* d_ws, size_t ws_size,
                              hipStream_t stream) {
    const float* x       = (const float*)d_in[0];
    const float* conv1_w = (const float*)d_in[1];
    const float* conv2_w = (const float*)d_in[2];
    const float* f_w  = (const float*)d_in[3];
    const float* f_b  = (const float*)d_in[4];
    const float* f_bw = (const float*)d_in[5];
    const float* f_bb = (const float*)d_in[6];
    const float* f_bm = (const float*)d_in[7];
    const float* f_bv = (const float*)d_in[8];
    const float* g_w  = (const float*)d_in[9];
    const float* g_b  = (const float*)d_in[10];
    const float* g_bw = (const float*)d_in[11];
    const float* g_bb = (const float*)d_in[12];
    const float* g_bm = (const float*)d_in[13];
    const float* g_bv = (const float*)d_in[14];
    const float* gamma = (const float*)d_in[15];
    const float* h_w  = (const float*)d_in[16];
    const float* h_b  = (const float*)d_in[17];
    const float* h_bw = (const float*)d_in[18];
    const float* h_bb = (const float*)d_in[19];
    const float* h_bm = (const float*)d_in[20];
    const float* h_bv = (const float*)d_in[21];
    const float* i_w  = (const float*)d_in[22];
    const float* i_b  = (const float*)d_in[23];
    const float* i_bw = (const float*)d_in[24];
    const float* i_bb = (const float*)d_in[25];
    const float* i_bm = (const float*)d_in[26];
    const float* i_bv = (const float*)d_in[27];

    float* ws   = (float*)d_ws;
    float* out1 = ws;                 // 1,048,576 floats (4 MB)
    float* fbuf = ws + 1048576;       //   131,072
    float* gh   = ws + 1179648;       //   262,144
    float* obuf = ws + 1441792;       //   131,072
    float* out2 = ws + 1572864;       // 1,048,576 (4 MB) — also Mpart/Dpart/opA
    float* Mpart = out2;              //   524,288 (dead before opA used)
    float* Dpart = out2 + 524288;     //   524,288
    float* opA   = out2;              // 1,048,576 (8 chunks x 131072)
    float* opB   = (float*)d_out;     // 1,048,576 (8 chunks) — scratch until conv2

    // K1: conv1
    conv3x3_k<<<dim3(16, 8, 4), 256, 0, stream>>>(x, conv1_w, out1);

    // K2: f/g/h projections + BN (+gamma), packed gh; f pre-scaled by L2E
    proj_k<<<256, 64, 0, stream>>>(out1,
        f_w, f_b, f_bw, f_bb, f_bm, f_bv,
        g_w, g_b, g_bw, g_bb, g_bm, g_bv,
        h_w, h_b, h_bw, h_bb, h_bm, h_bv,
        gamma, fbuf, gh);

    // K3: partial column stats (32 n-chunks)
    pass1_k<<<dim3(8, 32, 4), 256, 0, stream>>>(fbuf, gh, Mpart, Dpart);

    // K4: combine stats; fold 2^-M / D into h
    reduce1_k<<<256, 64, 0, stream>>>(Mpart, Dpart, gh);

    // K5: o partials (16 m-chunks)
    pass2_k<<<dim3(16, 16, 4), 256, 0, stream>>>(fbuf, gh, opA, opB);

    // K6: sum partials
    reduce2_k<<<256, 64, 0, stream>>>(opA, opB, obuf);

    // K7: i-conv + BN + residual
    post_k<<<4096, 256, 0, stream>>>(obuf, out1,
        i_w, i_b, i_bw, i_bb, i_bm, i_bv, out2);

    // K8: conv2 -> d_out
    conv3x3_k<<<dim3(16, 8, 4), 256, 0, stream>>>(out2, conv2_w, (float*)d_out);
}

// Round 5
// 178.908 us; speedup vs baseline: 2.1899x; 1.1067x over previous
//
#include <hip/hip_runtime.h>

#define EPSBN 1e-5f
#define L2E 1.44269504088896340736f

typedef __attribute__((ext_vector_type(2))) float f32x2;

__device__ __forceinline__ f32x2 pk_fma(f32x2 a, f32x2 b, f32x2 c) {
    f32x2 d;
    asm("v_pk_fma_f32 %0, %1, %2, %3" : "=v"(d) : "v"(a), "v"(b), "v"(c));
    return d;
}
__device__ __forceinline__ f32x2 pk_mul(f32x2 a, f32x2 b) {
    f32x2 d;
    asm("v_pk_mul_f32 %0, %1, %2" : "=v"(d) : "v"(a), "v"(b));
    return d;
}

// ---------------------------------------------------------------------------
// K1/K8: direct 3x3 conv, 64->64 ch, pad 1, fp32, LDS-staged.
// grid (16 rowbands, 8 cogroups, B), block 256.
// ---------------------------------------------------------------------------
__global__ __launch_bounds__(256) void conv3x3_k(
    const float* __restrict__ x, const float* __restrict__ w,
    float* __restrict__ y)
{
    __shared__ float xs[32][6][64];   // 48 KB

    const int b   = blockIdx.z;
    const int cob = blockIdx.y * 8;
    const int r0  = blockIdx.x * 4;
    const int row = threadIdx.x >> 6;   // 0..3
    const int col = threadIdx.x & 63;

    float acc[8];
#pragma unroll
    for (int j = 0; j < 8; ++j) acc[j] = 0.f;

    const float* xb = x + ((size_t)b << 18);
    const float* wb = w + cob * 576;

    const int lane16 = threadIdx.x & 15;
    const int pair0  = threadIdx.x >> 4;   // 0..15

    for (int cc = 0; cc < 2; ++cc) {
        const int ci0 = cc << 5;

        __syncthreads();
#pragma unroll
        for (int i = 0; i < 12; ++i) {
            const int pairIdx = i * 16 + pair0;   // 0..191
            const int rt  = pairIdx >> 5;          // 0..5
            const int cil = pairIdx & 31;          // 0..31
            const int gr  = r0 - 1 + rt;
            float4 v = make_float4(0.f, 0.f, 0.f, 0.f);
            if ((unsigned)gr < 64u)
                v = *(const float4*)(xb + (((size_t)(ci0 + cil)) << 12)
                                        + (gr << 6) + (lane16 << 2));
            *(float4*)&xs[cil][rt][lane16 << 2] = v;
        }
        __syncthreads();

        for (int ci = 0; ci < 32; ++ci) {
#pragma unroll
            for (int kh = 0; kh < 3; ++kh) {
                const int rt = row + kh;
                float wr[8][3];
#pragma unroll
                for (int j = 0; j < 8; ++j)
#pragma unroll
                    for (int k = 0; k < 3; ++k)
                        wr[j][k] = wb[j * 576 + (ci0 + ci) * 9 + kh * 3 + k];

                const float xm  = xs[ci][rt][col];
                const float xlv = xs[ci][rt][col - (col > 0 ? 1 : 0)];
                const float xl  = (col > 0) ? xlv : 0.f;
                const float xrv = xs[ci][rt][col + (col < 63 ? 1 : 0)];
                const float xr_ = (col < 63) ? xrv : 0.f;
#pragma unroll
                for (int j = 0; j < 8; ++j) {
                    acc[j] = fmaf(xl,  wr[j][0], acc[j]);
                    acc[j] = fmaf(xm,  wr[j][1], acc[j]);
                    acc[j] = fmaf(xr_, wr[j][2], acc[j]);
                }
            }
        }
    }

    float* yp = y + (((size_t)(b * 64 + cob)) << 12) + ((r0 + row) << 6) + col;
#pragma unroll
    for (int j = 0; j < 8; ++j) yp[(size_t)j << 12] = acc[j];
}

// ---------------------------------------------------------------------------
// K2: f/g/h 1x1-conv projections + bias + BN (+gamma for h).
// f [B*N][8] pre-scaled by L2E; gh[B*N][16] = {g[8], h[8]}.
// ---------------------------------------------------------------------------
__global__ __launch_bounds__(64) void proj_k(
    const float* __restrict__ out1,
    const float* __restrict__ f_w, const float* __restrict__ f_b,
    const float* __restrict__ f_bw, const float* __restrict__ f_bb,
    const float* __restrict__ f_bm, const float* __restrict__ f_bv,
    const float* __restrict__ g_w, const float* __restrict__ g_b,
    const float* __restrict__ g_bw, const float* __restrict__ g_bb,
    const float* __restrict__ g_bm, const float* __restrict__ g_bv,
    const float* __restrict__ h_w, const float* __restrict__ h_b,
    const float* __restrict__ h_bw, const float* __restrict__ h_bb,
    const float* __restrict__ h_bm, const float* __restrict__ h_bv,
    const float* __restrict__ gamma,
    float* __restrict__ f, float* __restrict__ gh)
{
    const int t = blockIdx.x * 64 + threadIdx.x;   // over B*N = 16384
    const int b = t >> 12, p = t & 4095;

    const float* xp = out1 + ((size_t)b << 18) + p;

    float aF[8], aG[8], aH[8];
#pragma unroll
    for (int c = 0; c < 8; ++c) { aF[c] = 0.f; aG[c] = 0.f; aH[c] = 0.f; }

    for (int ci = 0; ci < 64; ++ci) {
        const float xv = xp[ci << 12];
#pragma unroll
        for (int c = 0; c < 8; ++c) {
            aF[c] += xv * f_w[c * 64 + ci];
            aG[c] += xv * g_w[c * 64 + ci];
            aH[c] += xv * h_w[c * 64 + ci];
        }
    }

    const float gm = gamma[0];
    float fo[8], go[8], ho[8];
#pragma unroll
    for (int c = 0; c < 8; ++c) {
        float invf = f_bw[c] * rsqrtf(f_bv[c] + EPSBN);
        fo[c] = ((aF[c] + f_b[c]) * invf + (f_bb[c] - f_bm[c] * invf)) * L2E;
        float invg = g_bw[c] * rsqrtf(g_bv[c] + EPSBN);
        go[c] = (aG[c] + g_b[c]) * invg + (g_bb[c] - g_bm[c] * invg);
        float invh = h_bw[c] * rsqrtf(h_bv[c] + EPSBN);
        ho[c] = gm * ((aH[c] + h_b[c]) * invh + (h_bb[c] - h_bm[c] * invh));
    }

    float4* fp  = (float4*)(f + ((size_t)t << 3));
    float4* ghp = (float4*)(gh + ((size_t)t << 4));
    fp[0]  = make_float4(fo[0], fo[1], fo[2], fo[3]);
    fp[1]  = make_float4(fo[4], fo[5], fo[6], fo[7]);
    ghp[0] = make_float4(go[0], go[1], go[2], go[3]);
    ghp[1] = make_float4(go[4], go[5], go[6], go[7]);
    ghp[2] = make_float4(ho[0], ho[1], ho[2], ho[3]);
    ghp[3] = make_float4(ho[4], ho[5], ho[6], ho[7]);
}

// ---------------------------------------------------------------------------
// K3: partial column sums D[m] = sum_n 2^(f[n].g[m]) (no max: s bounded).
// Thread: 2 columns; n-chunk of 64 (blockIdx.y). grid (8, 64, B) = 2048 blk.
// f chunk staged in LDS (2 KB); packed-fp32 math.
// ---------------------------------------------------------------------------
__global__ __launch_bounds__(256) void pass1_k(
    const float* __restrict__ f, const float* __restrict__ gh,
    float* __restrict__ Dpart)
{
    __shared__ float4 fs[64][2];   // 2 KB: 64 n-rows x 8 floats

    const int b     = blockIdx.z;
    const int chunk = blockIdx.y;                     // 0..63
    const int q     = blockIdx.x * 256 + threadIdx.x; // 0..2047
    const int c0    = q << 1;

    f32x2 g0[4], g1[4];
    {
        const f32x2* gp0 = (const f32x2*)(gh + (((size_t)(b * 4096 + c0)) << 4));
        const f32x2* gp1 = (const f32x2*)(gh + (((size_t)(b * 4096 + c0 + 1)) << 4));
#pragma unroll
        for (int j = 0; j < 4; ++j) { g0[j] = gp0[j]; g1[j] = gp1[j]; }
    }

    if (threadIdx.x < 128) {
        const int r = threadIdx.x >> 1, hf = threadIdx.x & 1;
        fs[r][hf] = *(const float4*)(f + (((size_t)(b * 4096 + chunk * 64 + r)) << 3) + hf * 4);
    }
    __syncthreads();

    float D0 = 0.f, D1 = 0.f;

#pragma unroll 4
    for (int n = 0; n < 64; ++n) {
        const f32x2* fp = (const f32x2*)&fs[n][0];
        const f32x2 f0 = fp[0], f1 = fp[1], f2 = fp[2], f3 = fp[3];
        f32x2 s0 = pk_fma(f2, g0[2], pk_fma(f3, g0[3], pk_fma(f0, g0[0], pk_mul(f1, g0[1]))));
        f32x2 s1 = pk_fma(f2, g1[2], pk_fma(f3, g1[3], pk_fma(f0, g1[0], pk_mul(f1, g1[1]))));
        D0 += exp2f(s0.x + s0.y);
        D1 += exp2f(s1.x + s1.y);
    }

    const size_t o = (size_t)chunk * 16384 + b * 4096 + c0;
    *(float2*)(Dpart + o) = make_float2(D0, D1);
}

// ---------------------------------------------------------------------------
// K4: D = sum of 64 partials per column; fold 1/D into h half of gh.
// ---------------------------------------------------------------------------
__global__ __launch_bounds__(64) void reduce1_k(
    const float* __restrict__ Dpart, float* __restrict__ gh)
{
    const int t = blockIdx.x * 64 + threadIdx.x;   // column id over B*N

    float D = 0.f;
#pragma unroll 8
    for (int ch = 0; ch < 64; ++ch)
        D += Dpart[(size_t)ch * 16384 + t];
    const float scale = 1.f / D;

    float4* hp = (float4*)(gh + ((size_t)t << 4) + 8);
    float4 ha = hp[0], hb = hp[1];
    ha.x *= scale; ha.y *= scale; ha.z *= scale; ha.w *= scale;
    hb.x *= scale; hb.y *= scale; hb.z *= scale; hb.w *= scale;
    hp[0] = ha; hp[1] = hb;
}

// ---------------------------------------------------------------------------
// K5: o_partial[n,c] = sum_{m in chunk} 2^(f[n].g[m]) * h2[m,c]
// Thread: 1 row; m-chunk of 256 (blockIdx.y). grid (16, 16, B).
// gh chunk staged in LDS (16 KB); packed-fp32 math.
// ---------------------------------------------------------------------------
__global__ __launch_bounds__(256) void pass2_k(
    const float* __restrict__ f, const float* __restrict__ gh,
    float* __restrict__ opA, float* __restrict__ opB)
{
    __shared__ float4 ghs[256][4];   // 16 KB

    const int b     = blockIdx.z;
    const int chunk = blockIdx.y;                     // 0..15
    const int r     = blockIdx.x * 256 + threadIdx.x; // 0..4095

    f32x2 fr[4];
    {
        const f32x2* fp = (const f32x2*)(f + (((size_t)(b * 4096 + r)) << 3));
#pragma unroll
        for (int j = 0; j < 4; ++j) fr[j] = fp[j];
    }

    {
        const float4* src = (const float4*)(gh + (((size_t)(b * 4096 + chunk * 256)) << 4));
        float4* dst = &ghs[0][0];
#pragma unroll
        for (int k = 0; k < 4; ++k)
            dst[k * 256 + threadIdx.x] = src[k * 256 + threadIdx.x];
    }
    __syncthreads();

    f32x2 a0 = {0.f, 0.f}, a1 = {0.f, 0.f}, a2 = {0.f, 0.f}, a3 = {0.f, 0.f};

#pragma unroll 2
    for (int m = 0; m < 256; ++m) {
        const f32x2* row = (const f32x2*)&ghs[m][0];
        const f32x2 q0 = row[0], q1 = row[1], q2 = row[2], q3 = row[3];
        const f32x2 h0 = row[4], h1 = row[5], h2 = row[6], h3 = row[7];
        f32x2 s = pk_fma(q2, fr[2], pk_fma(q3, fr[3], pk_fma(q0, fr[0], pk_mul(q1, fr[1]))));
        const float e = exp2f(s.x + s.y);
        const f32x2 e2 = {e, e};
        a0 = pk_fma(e2, h0, a0);
        a1 = pk_fma(e2, h1, a1);
        a2 = pk_fma(e2, h2, a2);
        a3 = pk_fma(e2, h3, a3);
    }

    float* op = (chunk < 8) ? (opA + (size_t)chunk * 131072)
                            : (opB + (size_t)(chunk - 8) * 131072);
    float4* wv = (float4*)(op + (((size_t)(b * 4096 + r)) << 3));
    wv[0] = make_float4(a0.x, a0.y, a1.x, a1.y);
    wv[1] = make_float4(a2.x, a2.y, a3.x, a3.y);
}

// ---------------------------------------------------------------------------
// K6: sum 16 o-partials -> obuf[row][8].
// ---------------------------------------------------------------------------
__global__ __launch_bounds__(64) void reduce2_k(
    const float* __restrict__ opA, const float* __restrict__ opB,
    float* __restrict__ o)
{
    const int t = blockIdx.x * 64 + threadIdx.x;   // row id over B*N

    float a[8];
#pragma unroll
    for (int j = 0; j < 8; ++j) a[j] = 0.f;

#pragma unroll
    for (int ch = 0; ch < 16; ++ch) {
        const float* op = (ch < 8) ? (opA + (size_t)ch * 131072)
                                   : (opB + (size_t)(ch - 8) * 131072);
        const float4* p = (const float4*)(op + ((size_t)t << 3));
        const float4 pa = p[0], pb = p[1];
        a[0] += pa.x; a[1] += pa.y; a[2] += pa.z; a[3] += pa.w;
        a[4] += pb.x; a[5] += pb.y; a[6] += pb.z; a[7] += pb.w;
    }

    float4* wv = (float4*)(o + ((size_t)t << 3));
    wv[0] = make_float4(a[0], a[1], a[2], a[3]);
    wv[1] = make_float4(a[4], a[5], a[6], a[7]);
}

// ---------------------------------------------------------------------------
// K7: i 1x1-conv (8 -> 64) + bias + BN + residual with out1 -> out2.
// ---------------------------------------------------------------------------
__global__ __launch_bounds__(256) void post_k(
    const float* __restrict__ o, const float* __restrict__ out1,
    const float* __restrict__ i_w, const float* __restrict__ i_b,
    const float* __restrict__ i_bw, const float* __restrict__ i_bb,
    const float* __restrict__ i_bm, const float* __restrict__ i_bv,
    float* __restrict__ out2)
{
    const int idx = blockIdx.x * 256 + threadIdx.x;   // over B*64*4096
    const int p  = idx & 4095;
    const int co = (idx >> 12) & 63;
    const int b  = idx >> 18;

    const float4* op = (const float4*)(o + (((size_t)(b * 4096 + p)) << 3));
    const float4 oa = op[0], ob = op[1];
    const float* wp = i_w + co * 8;

    float v = oa.x * wp[0] + oa.y * wp[1] + oa.z * wp[2] + oa.w * wp[3]
            + ob.x * wp[4] + ob.y * wp[5] + ob.z * wp[6] + ob.w * wp[7];

    const float inv = i_bw[co] * rsqrtf(i_bv[co] + EPSBN);
    out2[idx] = (v + i_b[co]) * inv + (i_bb[co] - i_bm[co] * inv) + out1[idx];
}

// ---------------------------------------------------------------------------
extern "C" void kernel_launch(void* const* d_in, const int* in_sizes, int n_in,
                              void* d_out, int out_size, void* d_ws, size_t ws_size,
                              hipStream_t stream) {
    const float* x       = (const float*)d_in[0];
    const float* conv1_w = (const float*)d_in[1];
    const float* conv2_w = (const float*)d_in[2];
    const float* f_w  = (const float*)d_in[3];
    const float* f_b  = (const float*)d_in[4];
    const float* f_bw = (const float*)d_in[5];
    const float* f_bb = (const float*)d_in[6];
    const float* f_bm = (const float*)d_in[7];
    const float* f_bv = (const float*)d_in[8];
    const float* g_w  = (const float*)d_in[9];
    const float* g_b  = (const float*)d_in[10];
    const float* g_bw = (const float*)d_in[11];
    const float* g_bb = (const float*)d_in[12];
    const float* g_bm = (const float*)d_in[13];
    const float* g_bv = (const float*)d_in[14];
    const float* gamma = (const float*)d_in[15];
    const float* h_w  = (const float*)d_in[16];
    const float* h_b  = (const float*)d_in[17];
    const float* h_bw = (const float*)d_in[18];
    const float* h_bb = (const float*)d_in[19];
    const float* h_bm = (const float*)d_in[20];
    const float* h_bv = (const float*)d_in[21];
    const float* i_w  = (const float*)d_in[22];
    const float* i_b  = (const float*)d_in[23];
    const float* i_bw = (const float*)d_in[24];
    const float* i_bb = (const float*)d_in[25];
    const float* i_bm = (const float*)d_in[26];
    const float* i_bv = (const float*)d_in[27];

    float* ws   = (float*)d_ws;
    float* out1 = ws;                 // 1,048,576 floats (4 MB)
    float* fbuf = ws + 1048576;       //   131,072
    float* gh   = ws + 1179648;       //   262,144
    float* obuf = ws + 1441792;       //   131,072
    float* out2 = ws + 1572864;       // 1,048,576 (4 MB) — also Dpart/opA
    float* Dpart = out2;              // 1,048,576 (64 chunks x 16384; dead before opA used)
    float* opA   = out2;              // 1,048,576 (8 chunks x 131072)
    float* opB   = (float*)d_out;     // 1,048,576 (8 chunks) — scratch until conv2

    // K1: conv1
    conv3x3_k<<<dim3(16, 8, 4), 256, 0, stream>>>(x, conv1_w, out1);

    // K2: f/g/h projections + BN (+gamma); f pre-scaled by L2E
    proj_k<<<256, 64, 0, stream>>>(out1,
        f_w, f_b, f_bw, f_bb, f_bm, f_bv,
        g_w, g_b, g_bw, g_bb, g_bm, g_bv,
        h_w, h_b, h_bw, h_bb, h_bm, h_bv,
        gamma, fbuf, gh);

    // K3: partial column sums (64 n-chunks)
    pass1_k<<<dim3(8, 64, 4), 256, 0, stream>>>(fbuf, gh, Dpart);

    // K4: combine; fold 1/D into h
    reduce1_k<<<256, 64, 0, stream>>>(Dpart, gh);

    // K5: o partials (16 m-chunks)
    pass2_k<<<dim3(16, 16, 4), 256, 0, stream>>>(fbuf, gh, opA, opB);

    // K6: sum partials
    reduce2_k<<<256, 64, 0, stream>>>(opA, opB, obuf);

    // K7: i-conv + BN + residual
    post_k<<<4096, 256, 0, stream>>>(obuf, out1,
        i_w, i_b, i_bw, i_bb, i_bm, i_bv, out2);

    // K8: conv2 -> d_out
    conv3x3_k<<<dim3(16, 8, 4), 256, 0, stream>>>(out2, conv2_w, (float*)d_out);
}

// Round 6
// 170.084 us; speedup vs baseline: 2.3036x; 1.0519x over previous
//
#include <hip/hip_runtime.h>

#define EPSBN 1e-5f
#define L2E 1.44269504088896340736f

typedef __attribute__((ext_vector_type(2))) float f32x2;

__device__ __forceinline__ f32x2 pk_fma(f32x2 a, f32x2 b, f32x2 c) {
    f32x2 d;
    asm("v_pk_fma_f32 %0, %1, %2, %3" : "=v"(d) : "v"(a), "v"(b), "v"(c));
    return d;
}
__device__ __forceinline__ f32x2 pk_mul(f32x2 a, f32x2 b) {
    f32x2 d;
    asm("v_pk_mul_f32 %0, %1, %2" : "=v"(d) : "v"(a), "v"(b));
    return d;
}

// ---------------------------------------------------------------------------
// K1/K8: direct 3x3 conv, 64->64 ch, pad 1, fp32, LDS-staged.
// grid (16 rowbands, 8 cogroups, B), block 256.
// ---------------------------------------------------------------------------
__global__ __launch_bounds__(256) void conv3x3_k(
    const float* __restrict__ x, const float* __restrict__ w,
    float* __restrict__ y)
{
    __shared__ float xs[32][6][64];   // 48 KB

    const int b   = blockIdx.z;
    const int cob = blockIdx.y * 8;
    const int r0  = blockIdx.x * 4;
    const int row = threadIdx.x >> 6;   // 0..3
    const int col = threadIdx.x & 63;

    float acc[8];
#pragma unroll
    for (int j = 0; j < 8; ++j) acc[j] = 0.f;

    const float* xb = x + ((size_t)b << 18);
    const float* wb = w + cob * 576;

    const int lane16 = threadIdx.x & 15;
    const int pair0  = threadIdx.x >> 4;   // 0..15

    for (int cc = 0; cc < 2; ++cc) {
        const int ci0 = cc << 5;

        __syncthreads();
#pragma unroll
        for (int i = 0; i < 12; ++i) {
            const int pairIdx = i * 16 + pair0;   // 0..191
            const int rt  = pairIdx >> 5;          // 0..5
            const int cil = pairIdx & 31;          // 0..31
            const int gr  = r0 - 1 + rt;
            float4 v = make_float4(0.f, 0.f, 0.f, 0.f);
            if ((unsigned)gr < 64u)
                v = *(const float4*)(xb + (((size_t)(ci0 + cil)) << 12)
                                        + (gr << 6) + (lane16 << 2));
            *(float4*)&xs[cil][rt][lane16 << 2] = v;
        }
        __syncthreads();

        for (int ci = 0; ci < 32; ++ci) {
#pragma unroll
            for (int kh = 0; kh < 3; ++kh) {
                const int rt = row + kh;
                float wr[8][3];
#pragma unroll
                for (int j = 0; j < 8; ++j)
#pragma unroll
                    for (int k = 0; k < 3; ++k)
                        wr[j][k] = wb[j * 576 + (ci0 + ci) * 9 + kh * 3 + k];

                const float xm  = xs[ci][rt][col];
                const float xlv = xs[ci][rt][col - (col > 0 ? 1 : 0)];
                const float xl  = (col > 0) ? xlv : 0.f;
                const float xrv = xs[ci][rt][col + (col < 63 ? 1 : 0)];
                const float xr_ = (col < 63) ? xrv : 0.f;
#pragma unroll
                for (int j = 0; j < 8; ++j) {
                    acc[j] = fmaf(xl,  wr[j][0], acc[j]);
                    acc[j] = fmaf(xm,  wr[j][1], acc[j]);
                    acc[j] = fmaf(xr_, wr[j][2], acc[j]);
                }
            }
        }
    }

    float* yp = y + (((size_t)(b * 64 + cob)) << 12) + ((r0 + row) << 6) + col;
#pragma unroll
    for (int j = 0; j < 8; ++j) yp[(size_t)j << 12] = acc[j];
}

// ---------------------------------------------------------------------------
// K2: f/g/h 1x1-conv projections + bias + BN (+gamma for h).
// f [B*N][8] pre-scaled by L2E; gh[B*N][16] = {g[8], h[8]}.
// ---------------------------------------------------------------------------
__global__ __launch_bounds__(64) void proj_k(
    const float* __restrict__ out1,
    const float* __restrict__ f_w, const float* __restrict__ f_b,
    const float* __restrict__ f_bw, const float* __restrict__ f_bb,
    const float* __restrict__ f_bm, const float* __restrict__ f_bv,
    const float* __restrict__ g_w, const float* __restrict__ g_b,
    const float* __restrict__ g_bw, const float* __restrict__ g_bb,
    const float* __restrict__ g_bm, const float* __restrict__ g_bv,
    const float* __restrict__ h_w, const float* __restrict__ h_b,
    const float* __restrict__ h_bw, const float* __restrict__ h_bb,
    const float* __restrict__ h_bm, const float* __restrict__ h_bv,
    const float* __restrict__ gamma,
    float* __restrict__ f, float* __restrict__ gh)
{
    const int t = blockIdx.x * 64 + threadIdx.x;   // over B*N = 16384
    const int b = t >> 12, p = t & 4095;

    const float* xp = out1 + ((size_t)b << 18) + p;

    float aF[8], aG[8], aH[8];
#pragma unroll
    for (int c = 0; c < 8; ++c) { aF[c] = 0.f; aG[c] = 0.f; aH[c] = 0.f; }

    for (int ci = 0; ci < 64; ++ci) {
        const float xv = xp[ci << 12];
#pragma unroll
        for (int c = 0; c < 8; ++c) {
            aF[c] += xv * f_w[c * 64 + ci];
            aG[c] += xv * g_w[c * 64 + ci];
            aH[c] += xv * h_w[c * 64 + ci];
        }
    }

    const float gm = gamma[0];
    float fo[8], go[8], ho[8];
#pragma unroll
    for (int c = 0; c < 8; ++c) {
        float invf = f_bw[c] * rsqrtf(f_bv[c] + EPSBN);
        fo[c] = ((aF[c] + f_b[c]) * invf + (f_bb[c] - f_bm[c] * invf)) * L2E;
        float invg = g_bw[c] * rsqrtf(g_bv[c] + EPSBN);
        go[c] = (aG[c] + g_b[c]) * invg + (g_bb[c] - g_bm[c] * invg);
        float invh = h_bw[c] * rsqrtf(h_bv[c] + EPSBN);
        ho[c] = gm * ((aH[c] + h_b[c]) * invh + (h_bb[c] - h_bm[c] * invh));
    }

    float4* fp  = (float4*)(f + ((size_t)t << 3));
    float4* ghp = (float4*)(gh + ((size_t)t << 4));
    fp[0]  = make_float4(fo[0], fo[1], fo[2], fo[3]);
    fp[1]  = make_float4(fo[4], fo[5], fo[6], fo[7]);
    ghp[0] = make_float4(go[0], go[1], go[2], go[3]);
    ghp[1] = make_float4(go[4], go[5], go[6], go[7]);
    ghp[2] = make_float4(ho[0], ho[1], ho[2], ho[3]);
    ghp[3] = make_float4(ho[4], ho[5], ho[6], ho[7]);
}

// ---------------------------------------------------------------------------
// K3: partial column sums D[m] = sum_n 2^(f[n].g[m]) (no max: s bounded).
// Thread: 2 columns; n-chunk of 64 (blockIdx.y). grid (8, 64, B) = 2048 blk.
// ---------------------------------------------------------------------------
__global__ __launch_bounds__(256, 8) void pass1_k(
    const float* __restrict__ f, const float* __restrict__ gh,
    float* __restrict__ Dpart)
{
    __shared__ float4 fs[64][2];   // 2 KB: 64 n-rows x 8 floats

    const int b     = blockIdx.z;
    const int chunk = blockIdx.y;                     // 0..63
    const int q     = blockIdx.x * 256 + threadIdx.x; // 0..2047
    const int c0    = q << 1;

    f32x2 g0[4], g1[4];
    {
        const f32x2* gp0 = (const f32x2*)(gh + (((size_t)(b * 4096 + c0)) << 4));
        const f32x2* gp1 = (const f32x2*)(gh + (((size_t)(b * 4096 + c0 + 1)) << 4));
#pragma unroll
        for (int j = 0; j < 4; ++j) { g0[j] = gp0[j]; g1[j] = gp1[j]; }
    }

    if (threadIdx.x < 128) {
        const int r = threadIdx.x >> 1, hf = threadIdx.x & 1;
        fs[r][hf] = *(const float4*)(f + (((size_t)(b * 4096 + chunk * 64 + r)) << 3) + hf * 4);
    }
    __syncthreads();

    float D0 = 0.f, D1 = 0.f;

#pragma unroll 4
    for (int n = 0; n < 64; ++n) {
        const f32x2* fp = (const f32x2*)&fs[n][0];
        const f32x2 f0 = fp[0], f1 = fp[1], f2 = fp[2], f3 = fp[3];
        f32x2 s0 = pk_fma(f2, g0[2], pk_fma(f3, g0[3], pk_fma(f0, g0[0], pk_mul(f1, g0[1]))));
        f32x2 s1 = pk_fma(f2, g1[2], pk_fma(f3, g1[3], pk_fma(f0, g1[0], pk_mul(f1, g1[1]))));
        D0 += __builtin_amdgcn_exp2f(s0.x + s0.y);
        D1 += __builtin_amdgcn_exp2f(s1.x + s1.y);
    }

    const size_t o = (size_t)chunk * 16384 + b * 4096 + c0;
    *(float2*)(Dpart + o) = make_float2(D0, D1);
}

// ---------------------------------------------------------------------------
// K4: D = sum of 64 partials per column; fold 1/D into h half of gh.
// ---------------------------------------------------------------------------
__global__ __launch_bounds__(64) void reduce1_k(
    const float* __restrict__ Dpart, float* __restrict__ gh)
{
    const int t = blockIdx.x * 64 + threadIdx.x;   // column id over B*N

    float D = 0.f;
#pragma unroll 8
    for (int ch = 0; ch < 64; ++ch)
        D += Dpart[(size_t)ch * 16384 + t];
    const float scale = 1.f / D;

    float4* hp = (float4*)(gh + ((size_t)t << 4) + 8);
    float4 ha = hp[0], hb = hp[1];
    ha.x *= scale; ha.y *= scale; ha.z *= scale; ha.w *= scale;
    hb.x *= scale; hb.y *= scale; hb.z *= scale; hb.w *= scale;
    hp[0] = ha; hp[1] = hb;
}

// ---------------------------------------------------------------------------
// K5: o_partial[n,c] = sum_{m in chunk} 2^(f[n].g[m]) * h2[m,c]
// Block: 128 rows x 2 m-halves (hf = tid>>7); m-chunk 256 staged in LDS.
// grid (32, 16, B) = 2048 blocks -> 8 blocks/CU, 32 waves/CU.
// ---------------------------------------------------------------------------
__global__ __launch_bounds__(256, 8) void pass2_k(
    const float* __restrict__ f, const float* __restrict__ gh,
    float* __restrict__ opA, float* __restrict__ opB)
{
    __shared__ float4 ghs[256][4];   // 16 KB

    const int b     = blockIdx.z;
    const int chunk = blockIdx.y;                     // 0..15
    const int rl    = threadIdx.x & 127;
    const int hf    = threadIdx.x >> 7;               // 0,1
    const int r     = blockIdx.x * 128 + rl;          // 0..4095

    f32x2 fr[4];
    {
        const f32x2* fp = (const f32x2*)(f + (((size_t)(b * 4096 + r)) << 3));
#pragma unroll
        for (int j = 0; j < 4; ++j) fr[j] = fp[j];
    }

    {
        const float4* src = (const float4*)(gh + (((size_t)(b * 4096 + chunk * 256)) << 4));
        float4* dst = &ghs[0][0];
#pragma unroll
        for (int k = 0; k < 4; ++k)
            dst[k * 256 + threadIdx.x] = src[k * 256 + threadIdx.x];
    }
    __syncthreads();

    f32x2 a0 = {0.f, 0.f}, a1 = {0.f, 0.f}, a2 = {0.f, 0.f}, a3 = {0.f, 0.f};

    const f32x2* rowbase = (const f32x2*)&ghs[hf << 7][0];

#pragma unroll 4
    for (int m = 0; m < 128; ++m) {
        const f32x2* row = rowbase + (m << 3);
        const f32x2 q0 = row[0], q1 = row[1], q2 = row[2], q3 = row[3];
        const f32x2 h0 = row[4], h1 = row[5], h2 = row[6], h3 = row[7];
        f32x2 s = pk_fma(q2, fr[2], pk_fma(q3, fr[3], pk_fma(q0, fr[0], pk_mul(q1, fr[1]))));
        const float e = __builtin_amdgcn_exp2f(s.x + s.y);
        const f32x2 e2 = {e, e};
        a0 = pk_fma(e2, h0, a0);
        a1 = pk_fma(e2, h1, a1);
        a2 = pk_fma(e2, h2, a2);
        a3 = pk_fma(e2, h3, a3);
    }

    __syncthreads();   // everyone done reading ghs
    if (hf) {
        float4* red = &ghs[rl][0];
        red[0] = make_float4(a0.x, a0.y, a1.x, a1.y);
        red[1] = make_float4(a2.x, a2.y, a3.x, a3.y);
    }
    __syncthreads();
    if (!hf) {
        const float4* red = &ghs[rl][0];
        const float4 r0 = red[0], r1 = red[1];
        float* op = (chunk < 8) ? (opA + (size_t)chunk * 131072)
                                : (opB + (size_t)(chunk - 8) * 131072);
        float4* wv = (float4*)(op + (((size_t)(b * 4096 + r)) << 3));
        wv[0] = make_float4(a0.x + r0.x, a0.y + r0.y, a1.x + r0.z, a1.y + r0.w);
        wv[1] = make_float4(a2.x + r1.x, a2.y + r1.y, a3.x + r1.z, a3.y + r1.w);
    }
}

// ---------------------------------------------------------------------------
// K6: sum 16 o-partials -> obuf[row][8].
// ---------------------------------------------------------------------------
__global__ __launch_bounds__(64) void reduce2_k(
    const float* __restrict__ opA, const float* __restrict__ opB,
    float* __restrict__ o)
{
    const int t = blockIdx.x * 64 + threadIdx.x;   // row id over B*N

    float a[8];
#pragma unroll
    for (int j = 0; j < 8; ++j) a[j] = 0.f;

#pragma unroll
    for (int ch = 0; ch < 16; ++ch) {
        const float* op = (ch < 8) ? (opA + (size_t)ch * 131072)
                                   : (opB + (size_t)(ch - 8) * 131072);
        const float4* p = (const float4*)(op + ((size_t)t << 3));
        const float4 pa = p[0], pb = p[1];
        a[0] += pa.x; a[1] += pa.y; a[2] += pa.z; a[3] += pa.w;
        a[4] += pb.x; a[5] += pb.y; a[6] += pb.z; a[7] += pb.w;
    }

    float4* wv = (float4*)(o + ((size_t)t << 3));
    wv[0] = make_float4(a[0], a[1], a[2], a[3]);
    wv[1] = make_float4(a[4], a[5], a[6], a[7]);
}

// ---------------------------------------------------------------------------
// K7: i 1x1-conv (8 -> 64) + bias + BN + residual with out1 -> out2.
// ---------------------------------------------------------------------------
__global__ __launch_bounds__(256) void post_k(
    const float* __restrict__ o, const float* __restrict__ out1,
    const float* __restrict__ i_w, const float* __restrict__ i_b,
    const float* __restrict__ i_bw, const float* __restrict__ i_bb,
    const float* __restrict__ i_bm, const float* __restrict__ i_bv,
    float* __restrict__ out2)
{
    const int idx = blockIdx.x * 256 + threadIdx.x;   // over B*64*4096
    const int p  = idx & 4095;
    const int co = (idx >> 12) & 63;
    const int b  = idx >> 18;

    const float4* op = (const float4*)(o + (((size_t)(b * 4096 + p)) << 3));
    const float4 oa = op[0], ob = op[1];
    const float* wp = i_w + co * 8;

    float v = oa.x * wp[0] + oa.y * wp[1] + oa.z * wp[2] + oa.w * wp[3]
            + ob.x * wp[4] + ob.y * wp[5] + ob.z * wp[6] + ob.w * wp[7];

    const float inv = i_bw[co] * rsqrtf(i_bv[co] + EPSBN);
    out2[idx] = (v + i_b[co]) * inv + (i_bb[co] - i_bm[co] * inv) + out1[idx];
}

// ---------------------------------------------------------------------------
extern "C" void kernel_launch(void* const* d_in, const int* in_sizes, int n_in,
                              void* d_out, int out_size, void* d_ws, size_t ws_size,
                              hipStream_t stream) {
    const float* x       = (const float*)d_in[0];
    const float* conv1_w = (const float*)d_in[1];
    const float* conv2_w = (const float*)d_in[2];
    const float* f_w  = (const float*)d_in[3];
    const float* f_b  = (const float*)d_in[4];
    const float* f_bw = (const float*)d_in[5];
    const float* f_bb = (const float*)d_in[6];
    const float* f_bm = (const float*)d_in[7];
    const float* f_bv = (const float*)d_in[8];
    const float* g_w  = (const float*)d_in[9];
    const float* g_b  = (const float*)d_in[10];
    const float* g_bw = (const float*)d_in[11];
    const float* g_bb = (const float*)d_in[12];
    const float* g_bm = (const float*)d_in[13];
    const float* g_bv = (const float*)d_in[14];
    const float* gamma = (const float*)d_in[15];
    const float* h_w  = (const float*)d_in[16];
    const float* h_b  = (const float*)d_in[17];
    const float* h_bw = (const float*)d_in[18];
    const float* h_bb = (const float*)d_in[19];
    const float* h_bm = (const float*)d_in[20];
    const float* h_bv = (const float*)d_in[21];
    const float* i_w  = (const float*)d_in[22];
    const float* i_b  = (const float*)d_in[23];
    const float* i_bw = (const float*)d_in[24];
    const float* i_bb = (const float*)d_in[25];
    const float* i_bm = (const float*)d_in[26];
    const float* i_bv = (const float*)d_in[27];

    float* ws   = (float*)d_ws;
    float* out1 = ws;                 // 1,048,576 floats (4 MB)
    float* fbuf = ws + 1048576;       //   131,072
    float* gh   = ws + 1179648;       //   262,144
    float* obuf = ws + 1441792;       //   131,072
    float* out2 = ws + 1572864;       // 1,048,576 (4 MB) — also Dpart/opA
    float* Dpart = out2;              // 1,048,576 (64 chunks x 16384; dead before opA used)
    float* opA   = out2;              // 1,048,576 (8 chunks x 131072)
    float* opB   = (float*)d_out;     // 1,048,576 (8 chunks) — scratch until conv2

    // K1: conv1
    conv3x3_k<<<dim3(16, 8, 4), 256, 0, stream>>>(x, conv1_w, out1);

    // K2: f/g/h projections + BN (+gamma); f pre-scaled by L2E
    proj_k<<<256, 64, 0, stream>>>(out1,
        f_w, f_b, f_bw, f_bb, f_bm, f_bv,
        g_w, g_b, g_bw, g_bb, g_bm, g_bv,
        h_w, h_b, h_bw, h_bb, h_bm, h_bv,
        gamma, fbuf, gh);

    // K3: partial column sums (64 n-chunks)
    pass1_k<<<dim3(8, 64, 4), 256, 0, stream>>>(fbuf, gh, Dpart);

    // K4: combine; fold 1/D into h
    reduce1_k<<<256, 64, 0, stream>>>(Dpart, gh);

    // K5: o partials (16 m-chunks, 2 halves per block)
    pass2_k<<<dim3(32, 16, 4), 256, 0, stream>>>(fbuf, gh, opA, opB);

    // K6: sum partials
    reduce2_k<<<256, 64, 0, stream>>>(opA, opB, obuf);

    // K7: i-conv + BN + residual
    post_k<<<4096, 256, 0, stream>>>(obuf, out1,
        i_w, i_b, i_bw, i_bb, i_bm, i_bv, out2);

    // K8: conv2 -> d_out
    conv3x3_k<<<dim3(16, 8, 4), 256, 0, stream>>>(out2, conv2_w, (float*)d_out);
}

// Round 7
// 150.567 us; speedup vs baseline: 2.6021x; 1.1296x over previous
//
#include <hip/hip_runtime.h>

#define EPSBN 1e-5f
#define L2E 1.44269504088896340736f

typedef __attribute__((ext_vector_type(2))) float f32x2;
typedef __attribute__((ext_vector_type(4))) float f32x4;
typedef __attribute__((ext_vector_type(8))) short bf16x8;

__device__ __forceinline__ f32x2 pk_fma(f32x2 a, f32x2 b, f32x2 c) {
    f32x2 d;
    asm("v_pk_fma_f32 %0, %1, %2, %3" : "=v"(d) : "v"(a), "v"(b), "v"(c));
    return d;
}
__device__ __forceinline__ f32x2 pk_mul(f32x2 a, f32x2 b) {
    f32x2 d;
    asm("v_pk_mul_f32 %0, %1, %2" : "=v"(d) : "v"(a), "v"(b));
    return d;
}

__device__ __forceinline__ unsigned short f2bf(float f) {
    unsigned u = __float_as_uint(f);
    u = (u + 0x7FFFu + ((u >> 16) & 1u)) >> 16;
    return (unsigned short)u;
}

// ---------------------------------------------------------------------------
// K0: weight transpose+convert: wt[t][co][ci] bf16  <-  w[co][ci][t] f32
// 36864 elements, grid 144 x 256.
// ---------------------------------------------------------------------------
__global__ __launch_bounds__(256) void wcvt_k(const float* __restrict__ w,
                                              unsigned short* __restrict__ wt)
{
    const int i = blockIdx.x * 256 + threadIdx.x;
    const int ci = i & 63, co = (i >> 6) & 63, t = i >> 12;
    wt[i] = f2bf(w[(co * 64 + ci) * 9 + t]);
}

// ---------------------------------------------------------------------------
// K1/K8: 3x3 conv via bf16 MFMA (fp32 accum). Block = 1 image row (64 pix)
// x 32 out-channels; grid (64 rows, 2 cogroups, B), 256 threads = 4 waves.
// K = 9 taps x 64 ci, split into 18 K-steps of 32.
// xs: pixel-major bf16 with +/-1 col halo; ci index XOR-swizzled by pix>>3.
// ---------------------------------------------------------------------------
__global__ __launch_bounds__(256) void conv3x3_k(
    const float* __restrict__ x, const unsigned short* __restrict__ wt,
    float* __restrict__ y)
{
    __shared__ unsigned short xs[3][66][72];   // 28,512 B
    __shared__ unsigned short ws[9][32][72];   // 41,472 B
    __shared__ float          ls[32][68];      //  8,704 B

    const int b  = blockIdx.z;
    const int cg = blockIdx.y;
    const int r0 = blockIdx.x;

    const int tid  = threadIdx.x;
    const int lane = tid & 63, grp = tid >> 6;

    const float* xb = x + ((size_t)b << 18);

    // stage x rows r0-1..r0+1 (bf16, pixel-major, swizzled ci)
    for (int i = grp; i < 192; i += 4) {
        const int kh = i >> 6, ci = i & 63;
        const int gr = r0 + kh - 1;
        float v = 0.f;
        if ((unsigned)gr < 64u) v = xb[((size_t)ci << 12) + (gr << 6) + lane];
        const int p = lane + 1;
        xs[kh][p][ci ^ (((p >> 3) & 7) << 3)] = f2bf(v);
    }
    // zero halo columns (pix 0 and 65), padded width included
    for (int i = tid; i < 216; i += 256) {          // 216 dwords = 6 rows x 36
        const int row = i / 36, off = (i % 36) * 2;
        const int kh = row >> 1, p = (row & 1) ? 65 : 0;
        *(unsigned*)&xs[kh][p][off] = 0u;
    }
    // stage this cogroup's weights: ws[t][co_local][ci]
    for (int i = tid; i < 4608; i += 256) {
        const int q = i & 15, co = (i >> 4) & 31, t = i >> 9;
        const ushort4 v = *(const ushort4*)(wt + (((t * 64 + (cg << 5) + co) << 6) + (q << 2)));
        *(ushort4*)&ws[t][co][q << 2] = v;
    }
    __syncthreads();

    const int lr = lane & 15, lk = lane >> 4;
    const int pixbase = (grp << 4) + lr;

    f32x4 acc0 = {0.f, 0.f, 0.f, 0.f};
    f32x4 acc1 = {0.f, 0.f, 0.f, 0.f};

#pragma unroll
    for (int t = 0; t < 9; ++t) {
        const int kh = t / 3, kw = t % 3;
        const int p  = pixbase + kw;                 // 0..65
        const int sw = ((p >> 3) & 7) << 3;
#pragma unroll
        for (int ch = 0; ch < 2; ++ch) {
            const int cio = (ch << 5) + (lk << 3);
            const bf16x8 a  = *(const bf16x8*)&xs[kh][p][cio ^ sw];
            const bf16x8 b0 = *(const bf16x8*)&ws[t][lr][cio];
            const bf16x8 b1 = *(const bf16x8*)&ws[t][16 + lr][cio];
            acc0 = __builtin_amdgcn_mfma_f32_16x16x32_bf16(a, b0, acc0, 0, 0, 0);
            acc1 = __builtin_amdgcn_mfma_f32_16x16x32_bf16(a, b1, acc1, 0, 0, 0);
        }
    }

    // C: col(co_local) = lane&15 (+16 for acc1), row(pixel) = (lane>>4)*4 + j
#pragma unroll
    for (int j = 0; j < 4; ++j) {
        const int pix = (grp << 4) + (lk << 2) + j;
        ls[lr][pix]      = acc0[j];
        ls[lr + 16][pix] = acc1[j];
    }
    __syncthreads();

    // coalesced store: thread -> (co_local = tid>>3, 8 pixels)
    const int co_l = tid >> 3, pq = (tid & 7) << 3;
    float* yp = y + (((size_t)((b << 6) + (cg << 5) + co_l)) << 12) + (r0 << 6) + pq;
    *(float4*)yp       = *(const float4*)&ls[co_l][pq];
    *(float4*)(yp + 4) = *(const float4*)&ls[co_l][pq + 4];
}

// ---------------------------------------------------------------------------
// K2: f/g/h 1x1-conv projections + bias + BN (+gamma for h).
// f [B*N][8] pre-scaled by L2E; gh[B*N][16] = {g[8], h[8]}.
// ---------------------------------------------------------------------------
__global__ __launch_bounds__(64) void proj_k(
    const float* __restrict__ out1,
    const float* __restrict__ f_w, const float* __restrict__ f_b,
    const float* __restrict__ f_bw, const float* __restrict__ f_bb,
    const float* __restrict__ f_bm, const float* __restrict__ f_bv,
    const float* __restrict__ g_w, const float* __restrict__ g_b,
    const float* __restrict__ g_bw, const float* __restrict__ g_bb,
    const float* __restrict__ g_bm, const float* __restrict__ g_bv,
    const float* __restrict__ h_w, const float* __restrict__ h_b,
    const float* __restrict__ h_bw, const float* __restrict__ h_bb,
    const float* __restrict__ h_bm, const float* __restrict__ h_bv,
    const float* __restrict__ gamma,
    float* __restrict__ f, float* __restrict__ gh)
{
    const int t = blockIdx.x * 64 + threadIdx.x;   // over B*N = 16384
    const int b = t >> 12, p = t & 4095;

    const float* xp = out1 + ((size_t)b << 18) + p;

    float aF[8], aG[8], aH[8];
#pragma unroll
    for (int c = 0; c < 8; ++c) { aF[c] = 0.f; aG[c] = 0.f; aH[c] = 0.f; }

    for (int ci = 0; ci < 64; ++ci) {
        const float xv = xp[ci << 12];
#pragma unroll
        for (int c = 0; c < 8; ++c) {
            aF[c] += xv * f_w[c * 64 + ci];
            aG[c] += xv * g_w[c * 64 + ci];
            aH[c] += xv * h_w[c * 64 + ci];
        }
    }

    const float gm = gamma[0];
    float fo[8], go[8], ho[8];
#pragma unroll
    for (int c = 0; c < 8; ++c) {
        float invf = f_bw[c] * rsqrtf(f_bv[c] + EPSBN);
        fo[c] = ((aF[c] + f_b[c]) * invf + (f_bb[c] - f_bm[c] * invf)) * L2E;
        float invg = g_bw[c] * rsqrtf(g_bv[c] + EPSBN);
        go[c] = (aG[c] + g_b[c]) * invg + (g_bb[c] - g_bm[c] * invg);
        float invh = h_bw[c] * rsqrtf(h_bv[c] + EPSBN);
        ho[c] = gm * ((aH[c] + h_b[c]) * invh + (h_bb[c] - h_bm[c] * invh));
    }

    float4* fp  = (float4*)(f + ((size_t)t << 3));
    float4* ghp = (float4*)(gh + ((size_t)t << 4));
    fp[0]  = make_float4(fo[0], fo[1], fo[2], fo[3]);
    fp[1]  = make_float4(fo[4], fo[5], fo[6], fo[7]);
    ghp[0] = make_float4(go[0], go[1], go[2], go[3]);
    ghp[1] = make_float4(go[4], go[5], go[6], go[7]);
    ghp[2] = make_float4(ho[0], ho[1], ho[2], ho[3]);
    ghp[3] = make_float4(ho[4], ho[5], ho[6], ho[7]);
}

// ---------------------------------------------------------------------------
// K3: partial column sums D[m] = sum_n 2^(f[n].g[m]) (no max: s bounded).
// ---------------------------------------------------------------------------
__global__ __launch_bounds__(256, 8) void pass1_k(
    const float* __restrict__ f, const float* __restrict__ gh,
    float* __restrict__ Dpart)
{
    __shared__ float4 fs[64][2];

    const int b     = blockIdx.z;
    const int chunk = blockIdx.y;                     // 0..63
    const int q     = blockIdx.x * 256 + threadIdx.x; // 0..2047
    const int c0    = q << 1;

    f32x2 g0[4], g1[4];
    {
        const f32x2* gp0 = (const f32x2*)(gh + (((size_t)(b * 4096 + c0)) << 4));
        const f32x2* gp1 = (const f32x2*)(gh + (((size_t)(b * 4096 + c0 + 1)) << 4));
#pragma unroll
        for (int j = 0; j < 4; ++j) { g0[j] = gp0[j]; g1[j] = gp1[j]; }
    }

    if (threadIdx.x < 128) {
        const int r = threadIdx.x >> 1, hf = threadIdx.x & 1;
        fs[r][hf] = *(const float4*)(f + (((size_t)(b * 4096 + chunk * 64 + r)) << 3) + hf * 4);
    }
    __syncthreads();

    float D0 = 0.f, D1 = 0.f;

#pragma unroll 4
    for (int n = 0; n < 64; ++n) {
        const f32x2* fp = (const f32x2*)&fs[n][0];
        const f32x2 f0 = fp[0], f1 = fp[1], f2 = fp[2], f3 = fp[3];
        f32x2 s0 = pk_fma(f2, g0[2], pk_fma(f3, g0[3], pk_fma(f0, g0[0], pk_mul(f1, g0[1]))));
        f32x2 s1 = pk_fma(f2, g1[2], pk_fma(f3, g1[3], pk_fma(f0, g1[0], pk_mul(f1, g1[1]))));
        D0 += __builtin_amdgcn_exp2f(s0.x + s0.y);
        D1 += __builtin_amdgcn_exp2f(s1.x + s1.y);
    }

    const size_t o = (size_t)chunk * 16384 + b * 4096 + c0;
    *(float2*)(Dpart + o) = make_float2(D0, D1);
}

// ---------------------------------------------------------------------------
// K4: D = sum of 64 partials per column; fold 1/D into h half of gh.
// ---------------------------------------------------------------------------
__global__ __launch_bounds__(64) void reduce1_k(
    const float* __restrict__ Dpart, float* __restrict__ gh)
{
    const int t = blockIdx.x * 64 + threadIdx.x;

    float D = 0.f;
#pragma unroll 8
    for (int ch = 0; ch < 64; ++ch)
        D += Dpart[(size_t)ch * 16384 + t];
    const float scale = 1.f / D;

    float4* hp = (float4*)(gh + ((size_t)t << 4) + 8);
    float4 ha = hp[0], hb = hp[1];
    ha.x *= scale; ha.y *= scale; ha.z *= scale; ha.w *= scale;
    hb.x *= scale; hb.y *= scale; hb.z *= scale; hb.w *= scale;
    hp[0] = ha; hp[1] = hb;
}

// ---------------------------------------------------------------------------
// K5: o_partial[n,c] = sum_{m in chunk} 2^(f[n].g[m]) * h2[m,c]
// Block: 128 rows x 2 m-halves; m-chunk 256 staged in LDS.
// ---------------------------------------------------------------------------
__global__ __launch_bounds__(256, 8) void pass2_k(
    const float* __restrict__ f, const float* __restrict__ gh,
    float* __restrict__ opA, float* __restrict__ opB)
{
    __shared__ float4 ghs[256][4];   // 16 KB

    const int b     = blockIdx.z;
    const int chunk = blockIdx.y;                     // 0..15
    const int rl    = threadIdx.x & 127;
    const int hf    = threadIdx.x >> 7;               // 0,1
    const int r     = blockIdx.x * 128 + rl;          // 0..4095

    f32x2 fr[4];
    {
        const f32x2* fp = (const f32x2*)(f + (((size_t)(b * 4096 + r)) << 3));
#pragma unroll
        for (int j = 0; j < 4; ++j) fr[j] = fp[j];
    }

    {
        const float4* src = (const float4*)(gh + (((size_t)(b * 4096 + chunk * 256)) << 4));
        float4* dst = &ghs[0][0];
#pragma unroll
        for (int k = 0; k < 4; ++k)
            dst[k * 256 + threadIdx.x] = src[k * 256 + threadIdx.x];
    }
    __syncthreads();

    f32x2 a0 = {0.f, 0.f}, a1 = {0.f, 0.f}, a2 = {0.f, 0.f}, a3 = {0.f, 0.f};

    const f32x2* rowbase = (const f32x2*)&ghs[hf << 7][0];

#pragma unroll 4
    for (int m = 0; m < 128; ++m) {
        const f32x2* row = rowbase + (m << 3);
        const f32x2 q0 = row[0], q1 = row[1], q2 = row[2], q3 = row[3];
        const f32x2 h0 = row[4], h1 = row[5], h2 = row[6], h3 = row[7];
        f32x2 s = pk_fma(q2, fr[2], pk_fma(q3, fr[3], pk_fma(q0, fr[0], pk_mul(q1, fr[1]))));
        const float e = __builtin_amdgcn_exp2f(s.x + s.y);
        const f32x2 e2 = {e, e};
        a0 = pk_fma(e2, h0, a0);
        a1 = pk_fma(e2, h1, a1);
        a2 = pk_fma(e2, h2, a2);
        a3 = pk_fma(e2, h3, a3);
    }

    __syncthreads();
    if (hf) {
        float4* red = &ghs[rl][0];
        red[0] = make_float4(a0.x, a0.y, a1.x, a1.y);
        red[1] = make_float4(a2.x, a2.y, a3.x, a3.y);
    }
    __syncthreads();
    if (!hf) {
        const float4* red = &ghs[rl][0];
        const float4 r0 = red[0], r1 = red[1];
        float* op = (chunk < 8) ? (opA + (size_t)chunk * 131072)
                                : (opB + (size_t)(chunk - 8) * 131072);
        float4* wv = (float4*)(op + (((size_t)(b * 4096 + r)) << 3));
        wv[0] = make_float4(a0.x + r0.x, a0.y + r0.y, a1.x + r0.z, a1.y + r0.w);
        wv[1] = make_float4(a2.x + r1.x, a2.y + r1.y, a3.x + r1.z, a3.y + r1.w);
    }
}

// ---------------------------------------------------------------------------
// K6: sum 16 o-partials -> obuf[row][8].
// ---------------------------------------------------------------------------
__global__ __launch_bounds__(64) void reduce2_k(
    const float* __restrict__ opA, const float* __restrict__ opB,
    float* __restrict__ o)
{
    const int t = blockIdx.x * 64 + threadIdx.x;

    float a[8];
#pragma unroll
    for (int j = 0; j < 8; ++j) a[j] = 0.f;

#pragma unroll
    for (int ch = 0; ch < 16; ++ch) {
        const float* op = (ch < 8) ? (opA + (size_t)ch * 131072)
                                   : (opB + (size_t)(ch - 8) * 131072);
        const float4* p = (const float4*)(op + ((size_t)t << 3));
        const float4 pa = p[0], pb = p[1];
        a[0] += pa.x; a[1] += pa.y; a[2] += pa.z; a[3] += pa.w;
        a[4] += pb.x; a[5] += pb.y; a[6] += pb.z; a[7] += pb.w;
    }

    float4* wv = (float4*)(o + ((size_t)t << 3));
    wv[0] = make_float4(a[0], a[1], a[2], a[3]);
    wv[1] = make_float4(a[4], a[5], a[6], a[7]);
}

// ---------------------------------------------------------------------------
// K7: i 1x1-conv (8 -> 64) + bias + BN + residual with out1 -> out2.
// ---------------------------------------------------------------------------
__global__ __launch_bounds__(256) void post_k(
    const float* __restrict__ o, const float* __restrict__ out1,
    const float* __restrict__ i_w, const float* __restrict__ i_b,
    const float* __restrict__ i_bw, const float* __restrict__ i_bb,
    const float* __restrict__ i_bm, const float* __restrict__ i_bv,
    float* __restrict__ out2)
{
    const int idx = blockIdx.x * 256 + threadIdx.x;
    const int p  = idx & 4095;
    const int co = (idx >> 12) & 63;
    const int b  = idx >> 18;

    const float4* op = (const float4*)(o + (((size_t)(b * 4096 + p)) << 3));
    const float4 oa = op[0], ob = op[1];
    const float* wp = i_w + co * 8;

    float v = oa.x * wp[0] + oa.y * wp[1] + oa.z * wp[2] + oa.w * wp[3]
            + ob.x * wp[4] + ob.y * wp[5] + ob.z * wp[6] + ob.w * wp[7];

    const float inv = i_bw[co] * rsqrtf(i_bv[co] + EPSBN);
    out2[idx] = (v + i_b[co]) * inv + (i_bb[co] - i_bm[co] * inv) + out1[idx];
}

// ---------------------------------------------------------------------------
extern "C" void kernel_launch(void* const* d_in, const int* in_sizes, int n_in,
                              void* d_out, int out_size, void* d_ws, size_t ws_size,
                              hipStream_t stream) {
    const float* x       = (const float*)d_in[0];
    const float* conv1_w = (const float*)d_in[1];
    const float* conv2_w = (const float*)d_in[2];
    const float* f_w  = (const float*)d_in[3];
    const float* f_b  = (const float*)d_in[4];
    const float* f_bw = (const float*)d_in[5];
    const float* f_bb = (const float*)d_in[6];
    const float* f_bm = (const float*)d_in[7];
    const float* f_bv = (const float*)d_in[8];
    const float* g_w  = (const float*)d_in[9];
    const float* g_b  = (const float*)d_in[10];
    const float* g_bw = (const float*)d_in[11];
    const float* g_bb = (const float*)d_in[12];
    const float* g_bm = (const float*)d_in[13];
    const float* g_bv = (const float*)d_in[14];
    const float* gamma = (const float*)d_in[15];
    const float* h_w  = (const float*)d_in[16];
    const float* h_b  = (const float*)d_in[17];
    const float* h_bw = (const float*)d_in[18];
    const float* h_bb = (const float*)d_in[19];
    const float* h_bm = (const float*)d_in[20];
    const float* h_bv = (const float*)d_in[21];
    const float* i_w  = (const float*)d_in[22];
    const float* i_b  = (const float*)d_in[23];
    const float* i_bw = (const float*)d_in[24];
    const float* i_bb = (const float*)d_in[25];
    const float* i_bm = (const float*)d_in[26];
    const float* i_bv = (const float*)d_in[27];

    float* ws   = (float*)d_ws;
    float* out1 = ws;                 // 1,048,576 floats (4 MB)
    float* fbuf = ws + 1048576;       //   131,072
    float* gh   = ws + 1179648;       //   262,144
    float* obuf = ws + 1441792;       //   131,072
    float* out2 = ws + 1572864;       // 1,048,576 (4 MB) — also Dpart/opA
    float* Dpart = out2;              // 1,048,576 (64 chunks x 16384; dead before opA used)
    float* opA   = out2;              // 1,048,576 (8 chunks x 131072)
    float* opB   = (float*)d_out;     // 1,048,576 (8 chunks) — scratch until conv2
    unsigned short* wtbuf = (unsigned short*)(ws + 2621440);  // 36,864 bf16 (18,432 floats)

    // K0a: conv1 weights -> bf16 [t][co][ci]
    wcvt_k<<<144, 256, 0, stream>>>(conv1_w, wtbuf);

    // K1: conv1 (MFMA)
    conv3x3_k<<<dim3(64, 2, 4), 256, 0, stream>>>(x, wtbuf, out1);

    // K2: f/g/h projections + BN (+gamma); f pre-scaled by L2E
    proj_k<<<256, 64, 0, stream>>>(out1,
        f_w, f_b, f_bw, f_bb, f_bm, f_bv,
        g_w, g_b, g_bw, g_bb, g_bm, g_bv,
        h_w, h_b, h_bw, h_bb, h_bm, h_bv,
        gamma, fbuf, gh);

    // K3: partial column sums (64 n-chunks)
    pass1_k<<<dim3(8, 64, 4), 256, 0, stream>>>(fbuf, gh, Dpart);

    // K4: combine; fold 1/D into h
    reduce1_k<<<256, 64, 0, stream>>>(Dpart, gh);

    // K5: o partials (16 m-chunks, 2 halves per block)
    pass2_k<<<dim3(32, 16, 4), 256, 0, stream>>>(fbuf, gh, opA, opB);

    // K6: sum partials
    reduce2_k<<<256, 64, 0, stream>>>(opA, opB, obuf);

    // K7: i-conv + BN + residual
    post_k<<<4096, 256, 0, stream>>>(obuf, out1,
        i_w, i_b, i_bw, i_bb, i_bm, i_bv, out2);

    // K0b: conv2 weights -> bf16 (stream-ordered reuse of wtbuf)
    wcvt_k<<<144, 256, 0, stream>>>(conv2_w, wtbuf);

    // K8: conv2 (MFMA) -> d_out
    conv3x3_k<<<dim3(64, 2, 4), 256, 0, stream>>>(out2, wtbuf, (float*)d_out);
}

// Round 9
// 119.136 us; speedup vs baseline: 3.2887x; 1.2638x over previous
//
#include <hip/hip_runtime.h>

#define EPSBN 1e-5f
#define L2E 1.44269504088896340736f

typedef __attribute__((ext_vector_type(4)))  float f32x4;
typedef __attribute__((ext_vector_type(16))) float f32x16;
typedef __attribute__((ext_vector_type(8)))  short bf16x8;

__device__ __forceinline__ unsigned short f2bf(float f) {
    unsigned u = __float_as_uint(f);
    u = (u + 0x7FFFu + ((u >> 16) & 1u)) >> 16;
    return (unsigned short)u;
}
__device__ __forceinline__ float bf2f(unsigned short h) {
    return __uint_as_float((unsigned)h << 16);
}
__device__ __forceinline__ unsigned cvt_pk_bf16(float lo, float hi) {
    unsigned r;
    asm("v_cvt_pk_bf16_f32 %0, %1, %2" : "=v"(r) : "v"(lo), "v"(hi));
    return r;
}

// ---------------------------------------------------------------------------
// K0: weight transpose+convert: wt[t][co][ci] bf16  <-  w[co][ci][t] f32
// ---------------------------------------------------------------------------
__global__ __launch_bounds__(256) void wcvt_k(const float* __restrict__ w,
                                              unsigned short* __restrict__ wt)
{
    const int i = blockIdx.x * 256 + threadIdx.x;
    const int ci = i & 63, co = (i >> 6) & 63, t = i >> 12;
    wt[i] = f2bf(w[(co * 64 + ci) * 9 + t]);
}

// ---------------------------------------------------------------------------
// K1/K8: 3x3 conv via bf16 MFMA (fp32 accum). Block = 1 image row x 32 co.
// ---------------------------------------------------------------------------
__global__ __launch_bounds__(256) void conv3x3_k(
    const float* __restrict__ x, const unsigned short* __restrict__ wt,
    float* __restrict__ y)
{
    __shared__ unsigned short xs[3][66][72];
    __shared__ unsigned short ws[9][32][72];
    __shared__ float          ls[32][68];

    const int b  = blockIdx.z;
    const int cg = blockIdx.y;
    const int r0 = blockIdx.x;

    const int tid  = threadIdx.x;
    const int lane = tid & 63, grp = tid >> 6;

    const float* xb = x + ((size_t)b << 18);

    for (int i = grp; i < 192; i += 4) {
        const int kh = i >> 6, ci = i & 63;
        const int gr = r0 + kh - 1;
        float v = 0.f;
        if ((unsigned)gr < 64u) v = xb[((size_t)ci << 12) + (gr << 6) + lane];
        const int p = lane + 1;
        xs[kh][p][ci ^ (((p >> 3) & 7) << 3)] = f2bf(v);
    }
    for (int i = tid; i < 216; i += 256) {
        const int row = i / 36, off = (i % 36) * 2;
        const int kh = row >> 1, p = (row & 1) ? 65 : 0;
        *(unsigned*)&xs[kh][p][off] = 0u;
    }
    for (int i = tid; i < 4608; i += 256) {
        const int q = i & 15, co = (i >> 4) & 31, t = i >> 9;
        const ushort4 v = *(const ushort4*)(wt + (((t * 64 + (cg << 5) + co) << 6) + (q << 2)));
        *(ushort4*)&ws[t][co][q << 2] = v;
    }
    __syncthreads();

    const int lr = lane & 15, lk = lane >> 4;
    const int pixbase = (grp << 4) + lr;

    f32x4 acc0 = {0.f, 0.f, 0.f, 0.f};
    f32x4 acc1 = {0.f, 0.f, 0.f, 0.f};

#pragma unroll
    for (int t = 0; t < 9; ++t) {
        const int kh = t / 3, kw = t % 3;
        const int p  = pixbase + kw;
        const int sw = ((p >> 3) & 7) << 3;
#pragma unroll
        for (int ch = 0; ch < 2; ++ch) {
            const int cio = (ch << 5) + (lk << 3);
            const bf16x8 a  = *(const bf16x8*)&xs[kh][p][cio ^ sw];
            const bf16x8 b0 = *(const bf16x8*)&ws[t][lr][cio];
            const bf16x8 b1 = *(const bf16x8*)&ws[t][16 + lr][cio];
            acc0 = __builtin_amdgcn_mfma_f32_16x16x32_bf16(a, b0, acc0, 0, 0, 0);
            acc1 = __builtin_amdgcn_mfma_f32_16x16x32_bf16(a, b1, acc1, 0, 0, 0);
        }
    }

#pragma unroll
    for (int j = 0; j < 4; ++j) {
        const int pix = (grp << 4) + (lk << 2) + j;
        ls[lr][pix]      = acc0[j];
        ls[lr + 16][pix] = acc1[j];
    }
    __syncthreads();

    const int co_l = tid >> 3, pq = (tid & 7) << 3;
    float* yp = y + (((size_t)((b << 6) + (cg << 5) + co_l)) << 12) + (r0 << 6) + pq;
    *(float4*)yp       = *(const float4*)&ls[co_l][pq];
    *(float4*)(yp + 4) = *(const float4*)&ls[co_l][pq + 4];
}

// ---------------------------------------------------------------------------
// K2: f/g/h 1x1-conv projections + bias + BN (+gamma for h).
// f,g -> bf16 hi/lo pairs [B*N][16] = {hi[8], lo[8]} (f pre-scaled by L2E);
// h -> f32 [B*N][8]. The hi/lo split is exact: x = hi + lo to ~2^-17 rel.
// ---------------------------------------------------------------------------
__global__ __launch_bounds__(64) void proj_k(
    const float* __restrict__ out1,
    const float* __restrict__ f_w, const float* __restrict__ f_b,
    const float* __restrict__ f_bw, const float* __restrict__ f_bb,
    const float* __restrict__ f_bm, const float* __restrict__ f_bv,
    const float* __restrict__ g_w, const float* __restrict__ g_b,
    const float* __restrict__ g_bw, const float* __restrict__ g_bb,
    const float* __restrict__ g_bm, const float* __restrict__ g_bv,
    const float* __restrict__ h_w, const float* __restrict__ h_b,
    const float* __restrict__ h_bw, const float* __restrict__ h_bb,
    const float* __restrict__ h_bm, const float* __restrict__ h_bv,
    const float* __restrict__ gamma,
    unsigned short* __restrict__ fb, unsigned short* __restrict__ gb,
    float* __restrict__ hb)
{
    const int t = blockIdx.x * 64 + threadIdx.x;   // over B*N = 16384
    const int b = t >> 12, p = t & 4095;

    const float* xp = out1 + ((size_t)b << 18) + p;

    float aF[8], aG[8], aH[8];
#pragma unroll
    for (int c = 0; c < 8; ++c) { aF[c] = 0.f; aG[c] = 0.f; aH[c] = 0.f; }

    for (int ci = 0; ci < 64; ++ci) {
        const float xv = xp[ci << 12];
#pragma unroll
        for (int c = 0; c < 8; ++c) {
            aF[c] += xv * f_w[c * 64 + ci];
            aG[c] += xv * g_w[c * 64 + ci];
            aH[c] += xv * h_w[c * 64 + ci];
        }
    }

    const float gm = gamma[0];
    float fo[8], go[8], ho[8];
#pragma unroll
    for (int c = 0; c < 8; ++c) {
        float invf = f_bw[c] * rsqrtf(f_bv[c] + EPSBN);
        fo[c] = ((aF[c] + f_b[c]) * invf + (f_bb[c] - f_bm[c] * invf)) * L2E;
        float invg = g_bw[c] * rsqrtf(g_bv[c] + EPSBN);
        go[c] = (aG[c] + g_b[c]) * invg + (g_bb[c] - g_bm[c] * invg);
        float invh = h_bw[c] * rsqrtf(h_bv[c] + EPSBN);
        ho[c] = gm * ((aH[c] + h_b[c]) * invh + (h_bb[c] - h_bm[c] * invh));
    }

    unsigned short fhi[8], flo[8], ghi[8], glo[8];
#pragma unroll
    for (int c = 0; c < 8; ++c) {
        fhi[c] = f2bf(fo[c]);
        flo[c] = f2bf(fo[c] - bf2f(fhi[c]));
        ghi[c] = f2bf(go[c]);
        glo[c] = f2bf(go[c] - bf2f(ghi[c]));
    }
    uint4 fA, fB, gA, gB;
    fA.x = (unsigned)fhi[0] | ((unsigned)fhi[1] << 16);
    fA.y = (unsigned)fhi[2] | ((unsigned)fhi[3] << 16);
    fA.z = (unsigned)fhi[4] | ((unsigned)fhi[5] << 16);
    fA.w = (unsigned)fhi[6] | ((unsigned)fhi[7] << 16);
    fB.x = (unsigned)flo[0] | ((unsigned)flo[1] << 16);
    fB.y = (unsigned)flo[2] | ((unsigned)flo[3] << 16);
    fB.z = (unsigned)flo[4] | ((unsigned)flo[5] << 16);
    fB.w = (unsigned)flo[6] | ((unsigned)flo[7] << 16);
    gA.x = (unsigned)ghi[0] | ((unsigned)ghi[1] << 16);
    gA.y = (unsigned)ghi[2] | ((unsigned)ghi[3] << 16);
    gA.z = (unsigned)ghi[4] | ((unsigned)ghi[5] << 16);
    gA.w = (unsigned)ghi[6] | ((unsigned)ghi[7] << 16);
    gB.x = (unsigned)glo[0] | ((unsigned)glo[1] << 16);
    gB.y = (unsigned)glo[2] | ((unsigned)glo[3] << 16);
    gB.z = (unsigned)glo[4] | ((unsigned)glo[5] << 16);
    gB.w = (unsigned)glo[6] | ((unsigned)glo[7] << 16);

    *(uint4*)(fb + ((size_t)t << 4))     = fA;
    *(uint4*)(fb + ((size_t)t << 4) + 8) = fB;
    *(uint4*)(gb + ((size_t)t << 4))     = gA;
    *(uint4*)(gb + ((size_t)t << 4) + 8) = gB;

    float4* hp = (float4*)(hb + ((size_t)t << 3));
    hp[0] = make_float4(ho[0], ho[1], ho[2], ho[3]);
    hp[1] = make_float4(ho[4], ho[5], ho[6], ho[7]);
}

// ---------------------------------------------------------------------------
// K3: pass1 via MFMA with exact hi/lo QK.
// A-frag (G): lanes<32 load g_hi (k=0..7), lanes>=32 g_lo (k=8..15).
// B-frag: MFMA1 all lanes f_hi -> g.f_hi; MFMA2 all lanes f_lo -> += g.f_lo.
// T[m][n]: col n = lane&31, row m = (r&3)+8*(r>>2)+4*(lane>>5).
// grid (32 m-groups, 8 n-splits, B), block 256 (4 waves = 4 m-tiles).
// ---------------------------------------------------------------------------
__global__ __launch_bounds__(256) void pass1_k(
    const unsigned short* __restrict__ fb, const unsigned short* __restrict__ gb,
    float* __restrict__ Dpart)
{
    const int b   = blockIdx.z;
    const int ns  = blockIdx.y;             // 0..7
    const int mg  = blockIdx.x;             // 0..31
    const int wv  = threadIdx.x >> 6;
    const int l   = threadIdx.x & 63;
    const int col = l & 31;
    const int hl8 = (l >> 5) << 3;          // 0: hi half, 8: lo half
    const int mtile0 = (mg * 4 + wv) * 32;

    const bf16x8 Gf = *(const bf16x8*)(gb + (((size_t)b * 4096 + mtile0 + col) << 4) + hl8);

    const f32x16 Z = {0.f, 0.f, 0.f, 0.f, 0.f, 0.f, 0.f, 0.f,
                      0.f, 0.f, 0.f, 0.f, 0.f, 0.f, 0.f, 0.f};
    float Dacc[16];
#pragma unroll
    for (int r = 0; r < 16; ++r) Dacc[r] = 0.f;

    const unsigned short* fbase = fb + (((size_t)b * 4096 + ns * 512 + col) << 4);

    for (int nc = 0; nc < 16; ++nc) {
        const unsigned short* fr = fbase + ((size_t)nc << 9);   // +32 rows x 16
        const bf16x8 Fhi = *(const bf16x8*)(fr);
        const bf16x8 Flo = *(const bf16x8*)(fr + 8);
        f32x16 T = __builtin_amdgcn_mfma_f32_32x32x16_bf16(Gf, Fhi, Z, 0, 0, 0);
        T = __builtin_amdgcn_mfma_f32_32x32x16_bf16(Gf, Flo, T, 0, 0, 0);
#pragma unroll
        for (int r = 0; r < 16; ++r)
            Dacc[r] += __builtin_amdgcn_exp2f(T[r]);
    }

    // reduce across the 32 col-lanes (within each 32-lane half)
#pragma unroll
    for (int s = 1; s < 32; s <<= 1) {
#pragma unroll
        for (int r = 0; r < 16; ++r)
            Dacc[r] += __shfl_xor(Dacc[r], s);
    }

    if (col == 0) {   // lanes 0 (m-sets +0) and 32 (m-sets +4)
        const int hi4 = (l >> 5) << 2;
        float* dp = Dpart + (size_t)ns * 16384 + b * 4096 + mtile0;
#pragma unroll
        for (int r = 0; r < 16; ++r) {
            const int m = (r & 3) + ((r >> 2) << 3) + hi4;
            dp[m] = Dacc[r];
        }
    }
}

// ---------------------------------------------------------------------------
// K4: D = sum of 8 partials per column; write hT[b][c][m] = bf16(h*1/D).
// ---------------------------------------------------------------------------
__global__ __launch_bounds__(64) void reduce1_k(
    const float* __restrict__ Dpart, const float* __restrict__ hb,
    unsigned short* __restrict__ hT)
{
    const int t = blockIdx.x * 64 + threadIdx.x;   // column id over B*N
    const int b = t >> 12, m = t & 4095;

    float D = 0.f;
#pragma unroll
    for (int ch = 0; ch < 8; ++ch)
        D += Dpart[(size_t)ch * 16384 + t];
    const float scale = 1.f / D;

    const float4* hp = (const float4*)(hb + ((size_t)t << 3));
    const float4 h0 = hp[0], h1 = hp[1];
    unsigned short* o = hT + ((size_t)b << 15) + m;
    o[0]         = f2bf(h0.x * scale);
    o[4096]      = f2bf(h0.y * scale);
    o[2 * 4096]  = f2bf(h0.z * scale);
    o[3 * 4096]  = f2bf(h0.w * scale);
    o[4 * 4096]  = f2bf(h1.x * scale);
    o[5 * 4096]  = f2bf(h1.y * scale);
    o[6 * 4096]  = f2bf(h1.z * scale);
    o[7 * 4096]  = f2bf(h1.w * scale);
}

// ---------------------------------------------------------------------------
// K5: pass2 via MFMA with exact hi/lo QK.
// Per 32-m chunk: T = mfma(Gf,Fhi)+mfma(Gf,Flo) -> P = 2^T ->
// cvt_pk+shfl_xor(32) assemble PV B-frags -> O^T += mfma(hT-frag, P) x2.
// grid (128 n-tiles, 8 m-splits, B), block 64 (1 wave).
// ---------------------------------------------------------------------------
__global__ __launch_bounds__(64) void pass2_k(
    const unsigned short* __restrict__ fb, const unsigned short* __restrict__ gb,
    const unsigned short* __restrict__ hT, float* __restrict__ opPart)
{
    const int b   = blockIdx.z;
    const int ms  = blockIdx.y;             // 0..7
    const int nt  = blockIdx.x;             // 0..127
    const int l   = threadIdx.x & 63;
    const int col = l & 31;
    const bool lo = l < 32;
    const int hl8 = lo ? 0 : 8;

    const unsigned short* frow = fb + (((size_t)b * 4096 + nt * 32 + col) << 4);
    const bf16x8 Fhi = *(const bf16x8*)(frow);
    const bf16x8 Flo = *(const bf16x8*)(frow + 8);

    const f32x16 Z = {0.f, 0.f, 0.f, 0.f, 0.f, 0.f, 0.f, 0.f,
                      0.f, 0.f, 0.f, 0.f, 0.f, 0.f, 0.f, 0.f};
    f32x16 Oacc = Z;

    const unsigned short* gbase = gb + (((size_t)b * 4096 + ms * 512 + col) << 4);
    const unsigned short* hbase = hT + ((size_t)b << 15) + (size_t)col * 4096
                                     + ms * 512 + (lo ? 0 : 8);
    const bool hvalid = col < 8;

    for (int mc = 0; mc < 16; ++mc) {
        const bf16x8 Gf = *(const bf16x8*)(gbase + ((size_t)mc << 9) + hl8);
        f32x16 T = __builtin_amdgcn_mfma_f32_32x32x16_bf16(Gf, Fhi, Z, 0, 0, 0);
        T = __builtin_amdgcn_mfma_f32_32x32x16_bf16(Gf, Flo, T, 0, 0, 0);

        unsigned w[8];
#pragma unroll
        for (int p = 0; p < 8; ++p)
            w[p] = cvt_pk_bf16(__builtin_amdgcn_exp2f(T[2 * p]),
                               __builtin_amdgcn_exp2f(T[2 * p + 1]));

        const unsigned ea = __shfl_xor(lo ? w[2] : w[0], 32);
        const unsigned eb = __shfl_xor(lo ? w[3] : w[1], 32);
        const unsigned ec = __shfl_xor(lo ? w[6] : w[4], 32);
        const unsigned ed = __shfl_xor(lo ? w[7] : w[5], 32);

        union { unsigned u[4]; bf16x8 v; } B1, B2;
        B1.u[0] = lo ? w[0] : ea;  B1.u[1] = lo ? w[1] : eb;
        B1.u[2] = lo ? ea   : w[2]; B1.u[3] = lo ? eb   : w[3];
        B2.u[0] = lo ? w[4] : ec;  B2.u[1] = lo ? w[5] : ed;
        B2.u[2] = lo ? ec   : w[6]; B2.u[3] = lo ? ed   : w[7];

        bf16x8 A1 = {0, 0, 0, 0, 0, 0, 0, 0};
        bf16x8 A2 = {0, 0, 0, 0, 0, 0, 0, 0};
        if (hvalid) {
            A1 = *(const bf16x8*)(hbase + mc * 32);
            A2 = *(const bf16x8*)(hbase + mc * 32 + 16);
        }
        Oacc = __builtin_amdgcn_mfma_f32_32x32x16_bf16(A1, B1.v, Oacc, 0, 0, 0);
        Oacc = __builtin_amdgcn_mfma_f32_32x32x16_bf16(A2, B2.v, Oacc, 0, 0, 0);
    }

    // O^T: col n = lane&31; rows c = reg (0..3) + 4*(l>=32)
    float* op = opPart + (size_t)ms * 131072
              + (((size_t)b * 4096 + nt * 32 + col) << 3) + (lo ? 0 : 4);
    *(float4*)op = make_float4(Oacc[0], Oacc[1], Oacc[2], Oacc[3]);
}

// ---------------------------------------------------------------------------
// K6: sum 8 o-partials -> obuf[row][8].
// ---------------------------------------------------------------------------
__global__ __launch_bounds__(64) void reduce2_k(
    const float* __restrict__ opPart, float* __restrict__ o)
{
    const int t = blockIdx.x * 64 + threadIdx.x;

    float a[8];
#pragma unroll
    for (int j = 0; j < 8; ++j) a[j] = 0.f;

#pragma unroll
    for (int ch = 0; ch < 8; ++ch) {
        const float4* p = (const float4*)(opPart + (size_t)ch * 131072 + ((size_t)t << 3));
        const float4 pa = p[0], pb = p[1];
        a[0] += pa.x; a[1] += pa.y; a[2] += pa.z; a[3] += pa.w;
        a[4] += pb.x; a[5] += pb.y; a[6] += pb.z; a[7] += pb.w;
    }

    float4* wv = (float4*)(o + ((size_t)t << 3));
    wv[0] = make_float4(a[0], a[1], a[2], a[3]);
    wv[1] = make_float4(a[4], a[5], a[6], a[7]);
}

// ---------------------------------------------------------------------------
// K7: i 1x1-conv (8 -> 64) + bias + BN + residual with out1 -> out2.
// ---------------------------------------------------------------------------
__global__ __launch_bounds__(256) void post_k(
    const float* __restrict__ o, const float* __restrict__ out1,
    const float* __restrict__ i_w, const float* __restrict__ i_b,
    const float* __restrict__ i_bw, const float* __restrict__ i_bb,
    const float* __restrict__ i_bm, const float* __restrict__ i_bv,
    float* __restrict__ out2)
{
    const int idx = blockIdx.x * 256 + threadIdx.x;
    const int p  = idx & 4095;
    const int co = (idx >> 12) & 63;
    const int b  = idx >> 18;

    const float4* op = (const float4*)(o + (((size_t)(b * 4096 + p)) << 3));
    const float4 oa = op[0], ob = op[1];
    const float* wp = i_w + co * 8;

    float v = oa.x * wp[0] + oa.y * wp[1] + oa.z * wp[2] + oa.w * wp[3]
            + ob.x * wp[4] + ob.y * wp[5] + ob.z * wp[6] + ob.w * wp[7];

    const float inv = i_bw[co] * rsqrtf(i_bv[co] + EPSBN);
    out2[idx] = (v + i_b[co]) * inv + (i_bb[co] - i_bm[co] * inv) + out1[idx];
}

// ---------------------------------------------------------------------------
extern "C" void kernel_launch(void* const* d_in, const int* in_sizes, int n_in,
                              void* d_out, int out_size, void* d_ws, size_t ws_size,
                              hipStream_t stream) {
    const float* x       = (const float*)d_in[0];
    const float* conv1_w = (const float*)d_in[1];
    const float* conv2_w = (const float*)d_in[2];
    const float* f_w  = (const float*)d_in[3];
    const float* f_b  = (const float*)d_in[4];
    const float* f_bw = (const float*)d_in[5];
    const float* f_bb = (const float*)d_in[6];
    const float* f_bm = (const float*)d_in[7];
    const float* f_bv = (const float*)d_in[8];
    const float* g_w  = (const float*)d_in[9];
    const float* g_b  = (const float*)d_in[10];
    const float* g_bw = (const float*)d_in[11];
    const float* g_bb = (const float*)d_in[12];
    const float* g_bm = (const float*)d_in[13];
    const float* g_bv = (const float*)d_in[14];
    const float* gamma = (const float*)d_in[15];
    const float* h_w  = (const float*)d_in[16];
    const float* h_b  = (const float*)d_in[17];
    const float* h_bw = (const float*)d_in[18];
    const float* h_bb = (const float*)d_in[19];
    const float* h_bm = (const float*)d_in[20];
    const float* h_bv = (const float*)d_in[21];
    const float* i_w  = (const float*)d_in[22];
    const float* i_b  = (const float*)d_in[23];
    const float* i_bw = (const float*)d_in[24];
    const float* i_bb = (const float*)d_in[25];
    const float* i_bm = (const float*)d_in[26];
    const float* i_bv = (const float*)d_in[27];

    float* ws   = (float*)d_ws;
    float* out1 = ws;                                         // 1,048,576 f
    float* out2 = ws + 1048576;                               // 1,048,576 f
    unsigned short* fbuf = (unsigned short*)(ws + 2097152);   // 262,144 bf16 (hi/lo)
    unsigned short* gbuf = (unsigned short*)(ws + 2228224);   // 262,144 bf16 (hi/lo)
    float* hbuf = ws + 2359296;                               //   131,072 f
    unsigned short* hT   = (unsigned short*)(ws + 2490368);   // 131,072 bf16
    unsigned short* wtbuf = (unsigned short*)(ws + 2555904);  //  36,864 bf16
    float* Dpart = out2;          // 8 x 16,384 f — dead before post_k writes out2
    float* obuf  = hbuf;          // hbuf dead after reduce1_k
    float* opPart = (float*)d_out;   // 8 x 131,072 f — scratch until conv2

    // K0a: conv1 weights -> bf16 [t][co][ci]
    wcvt_k<<<144, 256, 0, stream>>>(conv1_w, wtbuf);

    // K1: conv1 (MFMA)
    conv3x3_k<<<dim3(64, 2, 4), 256, 0, stream>>>(x, wtbuf, out1);

    // K2: projections -> f,g bf16 hi/lo (f has L2E), h f32
    proj_k<<<256, 64, 0, stream>>>(out1,
        f_w, f_b, f_bw, f_bb, f_bm, f_bv,
        g_w, g_b, g_bw, g_bb, g_bm, g_bv,
        h_w, h_b, h_bw, h_bb, h_bm, h_bv,
        gamma, fbuf, gbuf, hbuf);

    // K3: pass1 MFMA: column sums D (8 n-splits)
    pass1_k<<<dim3(32, 8, 4), 256, 0, stream>>>(fbuf, gbuf, Dpart);

    // K4: combine D; build hT = bf16(h / D) transposed
    reduce1_k<<<256, 64, 0, stream>>>(Dpart, hbuf, hT);

    // K5: pass2 MFMA: O partials (8 m-splits)
    pass2_k<<<dim3(128, 8, 4), 64, 0, stream>>>(fbuf, gbuf, hT, opPart);

    // K6: sum partials -> obuf
    reduce2_k<<<256, 64, 0, stream>>>(opPart, obuf);

    // K7: i-conv + BN + residual
    post_k<<<4096, 256, 0, stream>>>(obuf, out1,
        i_w, i_b, i_bw, i_bb, i_bm, i_bv, out2);

    // K0b: conv2 weights -> bf16
    wcvt_k<<<144, 256, 0, stream>>>(conv2_w, wtbuf);

    // K8: conv2 (MFMA) -> d_out (overwrites opPart scratch)
    conv3x3_k<<<dim3(64, 2, 4), 256, 0, stream>>>(out2, wtbuf, (float*)d_out);
}

// Round 10
// 82.640 us; speedup vs baseline: 4.7410x; 1.4416x over previous
//
#include <hip/hip_runtime.h>

#define EPSBN 1e-5f
#define L2E 1.44269504088896340736f

typedef __attribute__((ext_vector_type(4)))  float f32x4;
typedef __attribute__((ext_vector_type(16))) float f32x16;
typedef __attribute__((ext_vector_type(8)))  short bf16x8;

__device__ __forceinline__ unsigned short f2bf(float f) {
    unsigned u = __float_as_uint(f);
    u = (u + 0x7FFFu + ((u >> 16) & 1u)) >> 16;
    return (unsigned short)u;
}
__device__ __forceinline__ float bf2f(unsigned short h) {
    return __uint_as_float((unsigned)h << 16);
}
__device__ __forceinline__ unsigned cvt_pk_bf16(float lo, float hi) {
    unsigned r;
    asm("v_cvt_pk_bf16_f32 %0, %1, %2" : "=v"(r) : "v"(lo), "v"(hi));
    return r;
}

// ---------------------------------------------------------------------------
// K0 prep: blocks 0..255: x (fp32 channel-major) -> xT bf16 pixel-major
//          blocks 256..291: conv1_w/conv2_w -> wt1/wt2 bf16 [t][co][ci]
// ---------------------------------------------------------------------------
__global__ __launch_bounds__(256) void prep_k(
    const float* __restrict__ x, const float* __restrict__ w1,
    const float* __restrict__ w2,
    unsigned short* __restrict__ xT, unsigned short* __restrict__ wt1,
    unsigned short* __restrict__ wt2)
{
    const int tid = threadIdx.x;
    if (blockIdx.x < 256) {
        __shared__ unsigned short tls[64][72];
        const int b = blockIdx.x >> 6, p0 = (blockIdx.x & 63) << 6;
        const int ci = tid >> 2, pq = tid & 3;
        const float* src = x + (((size_t)(b * 64 + ci)) << 12) + p0 + pq * 16;
#pragma unroll
        for (int j = 0; j < 4; ++j) {
            const float4 v = *(const float4*)(src + j * 4);
            const int pl = pq * 16 + j * 4;
            tls[pl][ci]     = f2bf(v.x);
            tls[pl + 1][ci] = f2bf(v.y);
            tls[pl + 2][ci] = f2bf(v.z);
            tls[pl + 3][ci] = f2bf(v.w);
        }
        __syncthreads();
        const int pix = tid >> 2, cg = tid & 3;
        const uint4 a  = *(const uint4*)&tls[pix][cg << 4];
        const uint4 b2 = *(const uint4*)&tls[pix][(cg << 4) + 8];
        unsigned short* dst = xT + (((size_t)((b << 12) + p0 + pix)) << 6) + (cg << 4);
        *(uint4*)dst       = a;
        *(uint4*)(dst + 8) = b2;
    } else {
        const int e0 = (blockIdx.x - 256) * 2048 + tid * 8;
#pragma unroll
        for (int j = 0; j < 8; ++j) {
            const int e = e0 + j;
            const int which = e >= 36864;
            const int je = which ? e - 36864 : e;
            const int t_ = je >> 12, co = (je >> 6) & 63, ci = je & 63;
            const float val = (which ? w2 : w1)[(co * 64 + ci) * 9 + t_];
            (which ? wt2 : wt1)[je] = f2bf(val);
        }
    }
}

// ---------------------------------------------------------------------------
// K1/K7: 3x3 conv via bf16 MFMA. Input = pixel-major bf16 xT[b][pix][ci].
// Block = 1 image row x 32 co; grid (64, 2, B). Output fp32 channel-major.
// ---------------------------------------------------------------------------
__global__ __launch_bounds__(256) void conv3x3_k(
    const unsigned short* __restrict__ xT, const unsigned short* __restrict__ wt,
    float* __restrict__ y)
{
    __shared__ unsigned short xs[3][66][72];
    __shared__ unsigned short ws[9][32][72];
    __shared__ float          ls[32][68];

    const int b  = blockIdx.z;
    const int cg = blockIdx.y;
    const int r0 = blockIdx.x;
    const int tid = threadIdx.x;

    // stage x rows r0-1..r0+1: 16B vector loads, 8-group-aligned ci swizzle
    for (int u = tid; u < 1536; u += 256) {
        const int kh = u >> 9, rem = u & 511;
        const int p = 1 + (rem >> 3), cig = rem & 7;
        const int gr = r0 + kh - 1;
        uint4 v = make_uint4(0u, 0u, 0u, 0u);
        if ((unsigned)gr < 64u)
            v = *(const uint4*)(xT + (((size_t)((b << 12) + (gr << 6) + (p - 1))) << 6) + (cig << 3));
        const int s = (p >> 3) & 7;
        *(uint4*)&xs[kh][p][(cig ^ s) << 3] = v;
    }
    if (tid < 48) {   // zero halo columns p=0, p=65 (swz=0 for both)
        const int kh = tid >> 4, pp = (tid & 8) ? 65 : 0, cig = tid & 7;
        *(uint4*)&xs[kh][pp][cig << 3] = make_uint4(0u, 0u, 0u, 0u);
    }
    // stage weights ws[t][co][ci]
    for (int u = tid; u < 2304; u += 256) {
        const int t_ = u >> 8, rem = u & 255;
        const int co = rem >> 3, cig = rem & 7;
        const uint4 v = *(const uint4*)(wt + (((t_ * 64) + (cg << 5) + co) << 6) + (cig << 3));
        *(uint4*)&ws[t_][co][cig << 3] = v;
    }
    __syncthreads();

    const int lane = tid & 63, grp = tid >> 6;
    const int lr = lane & 15, lk = lane >> 4;
    const int pixbase = (grp << 4) + lr;

    f32x4 acc0 = {0.f, 0.f, 0.f, 0.f};
    f32x4 acc1 = {0.f, 0.f, 0.f, 0.f};

#pragma unroll
    for (int t = 0; t < 9; ++t) {
        const int kh = t / 3, kw = t % 3;
        const int p  = pixbase + kw;
        const int sw = ((p >> 3) & 7) << 3;
#pragma unroll
        for (int ch = 0; ch < 2; ++ch) {
            const int cio = (ch << 5) + (lk << 3);
            const bf16x8 a  = *(const bf16x8*)&xs[kh][p][cio ^ sw];
            const bf16x8 b0 = *(const bf16x8*)&ws[t][lr][cio];
            const bf16x8 b1 = *(const bf16x8*)&ws[t][16 + lr][cio];
            acc0 = __builtin_amdgcn_mfma_f32_16x16x32_bf16(a, b0, acc0, 0, 0, 0);
            acc1 = __builtin_amdgcn_mfma_f32_16x16x32_bf16(a, b1, acc1, 0, 0, 0);
        }
    }

#pragma unroll
    for (int j = 0; j < 4; ++j) {
        const int pix = (grp << 4) + (lk << 2) + j;
        ls[lr][pix]      = acc0[j];
        ls[lr + 16][pix] = acc1[j];
    }
    __syncthreads();

    const int co_l = tid >> 3, pq = (tid & 7) << 3;
    float* yp = y + (((size_t)((b << 6) + (cg << 5) + co_l)) << 12) + (r0 << 6) + pq;
    *(float4*)yp       = *(const float4*)&ls[co_l][pq];
    *(float4*)(yp + 4) = *(const float4*)&ls[co_l][pq + 4];
}

// ---------------------------------------------------------------------------
// K2 proj: f/g/h 1x1-conv + bias + BN (+gamma). 4 threads/pixel (16 ci each),
// LDS combine. f,g -> bf16 hi/lo [B*N][16] (f pre-scaled by L2E); h -> f32.
// grid 256, block 256 (64 pixels/block).
// ---------------------------------------------------------------------------
__global__ __launch_bounds__(256) void proj_k(
    const float* __restrict__ out1,
    const float* __restrict__ f_w, const float* __restrict__ f_b,
    const float* __restrict__ f_bw, const float* __restrict__ f_bb,
    const float* __restrict__ f_bm, const float* __restrict__ f_bv,
    const float* __restrict__ g_w, const float* __restrict__ g_b,
    const float* __restrict__ g_bw, const float* __restrict__ g_bb,
    const float* __restrict__ g_bm, const float* __restrict__ g_bv,
    const float* __restrict__ h_w, const float* __restrict__ h_b,
    const float* __restrict__ h_bw, const float* __restrict__ h_bb,
    const float* __restrict__ h_bm, const float* __restrict__ h_bv,
    const float* __restrict__ gamma,
    unsigned short* __restrict__ fb, unsigned short* __restrict__ gb,
    float* __restrict__ hb)
{
    __shared__ float comb[3][64][25];

    const int pl = threadIdx.x >> 2, q = threadIdx.x & 3;
    const int pix = blockIdx.x * 64 + pl;
    const int b = pix >> 12, p = pix & 4095;
    const int cibase = q << 4;

    const float* xp = out1 + ((size_t)b << 18) + ((size_t)cibase << 12) + p;

    float aF[8], aG[8], aH[8];
#pragma unroll
    for (int c = 0; c < 8; ++c) { aF[c] = 0.f; aG[c] = 0.f; aH[c] = 0.f; }

#pragma unroll
    for (int ci = 0; ci < 16; ++ci) {
        const float xv = xp[(size_t)ci << 12];
#pragma unroll
        for (int c = 0; c < 8; ++c) {
            aF[c] = fmaf(xv, f_w[c * 64 + cibase + ci], aF[c]);
            aG[c] = fmaf(xv, g_w[c * 64 + cibase + ci], aG[c]);
            aH[c] = fmaf(xv, h_w[c * 64 + cibase + ci], aH[c]);
        }
    }

    if (q) {
        float* cp = comb[q - 1][pl];
#pragma unroll
        for (int c = 0; c < 8; ++c) { cp[c] = aF[c]; cp[8 + c] = aG[c]; cp[16 + c] = aH[c]; }
    }
    __syncthreads();
    if (q == 0) {
#pragma unroll
        for (int k = 0; k < 3; ++k) {
            const float* cp = comb[k][pl];
#pragma unroll
            for (int c = 0; c < 8; ++c) { aF[c] += cp[c]; aG[c] += cp[8 + c]; aH[c] += cp[16 + c]; }
        }

        const float gm = gamma[0];
        float fo[8], go[8], ho[8];
#pragma unroll
        for (int c = 0; c < 8; ++c) {
            float invf = f_bw[c] * rsqrtf(f_bv[c] + EPSBN);
            fo[c] = ((aF[c] + f_b[c]) * invf + (f_bb[c] - f_bm[c] * invf)) * L2E;
            float invg = g_bw[c] * rsqrtf(g_bv[c] + EPSBN);
            go[c] = (aG[c] + g_b[c]) * invg + (g_bb[c] - g_bm[c] * invg);
            float invh = h_bw[c] * rsqrtf(h_bv[c] + EPSBN);
            ho[c] = gm * ((aH[c] + h_b[c]) * invh + (h_bb[c] - h_bm[c] * invh));
        }

        unsigned short fhi[8], flo[8], ghi[8], glo[8];
#pragma unroll
        for (int c = 0; c < 8; ++c) {
            fhi[c] = f2bf(fo[c]);
            flo[c] = f2bf(fo[c] - bf2f(fhi[c]));
            ghi[c] = f2bf(go[c]);
            glo[c] = f2bf(go[c] - bf2f(ghi[c]));
        }
        uint4 fA, fB, gA, gB;
        fA.x = (unsigned)fhi[0] | ((unsigned)fhi[1] << 16);
        fA.y = (unsigned)fhi[2] | ((unsigned)fhi[3] << 16);
        fA.z = (unsigned)fhi[4] | ((unsigned)fhi[5] << 16);
        fA.w = (unsigned)fhi[6] | ((unsigned)fhi[7] << 16);
        fB.x = (unsigned)flo[0] | ((unsigned)flo[1] << 16);
        fB.y = (unsigned)flo[2] | ((unsigned)flo[3] << 16);
        fB.z = (unsigned)flo[4] | ((unsigned)flo[5] << 16);
        fB.w = (unsigned)flo[6] | ((unsigned)flo[7] << 16);
        gA.x = (unsigned)ghi[0] | ((unsigned)ghi[1] << 16);
        gA.y = (unsigned)ghi[2] | ((unsigned)ghi[3] << 16);
        gA.z = (unsigned)ghi[4] | ((unsigned)ghi[5] << 16);
        gA.w = (unsigned)ghi[6] | ((unsigned)ghi[7] << 16);
        gB.x = (unsigned)glo[0] | ((unsigned)glo[1] << 16);
        gB.y = (unsigned)glo[2] | ((unsigned)glo[3] << 16);
        gB.z = (unsigned)glo[4] | ((unsigned)glo[5] << 16);
        gB.w = (unsigned)glo[6] | ((unsigned)glo[7] << 16);

        *(uint4*)(fb + ((size_t)pix << 4))     = fA;
        *(uint4*)(fb + ((size_t)pix << 4) + 8) = fB;
        *(uint4*)(gb + ((size_t)pix << 4))     = gA;
        *(uint4*)(gb + ((size_t)pix << 4) + 8) = gB;

        float4* hp = (float4*)(hb + ((size_t)pix << 3));
        hp[0] = make_float4(ho[0], ho[1], ho[2], ho[3]);
        hp[1] = make_float4(ho[4], ho[5], ho[6], ho[7]);
    }
}

// ---------------------------------------------------------------------------
// K3 pass1 (fused reduce): block = one 32-m tile; 4 waves split n (1024 each).
// Exact hi/lo QK via 2 chained MFMAs. LDS-combine D; write hT = bf16(h/D).
// grid (128, B), block 256.
// ---------------------------------------------------------------------------
__global__ __launch_bounds__(256) void pass1_k(
    const unsigned short* __restrict__ fb, const unsigned short* __restrict__ gb,
    const float* __restrict__ hb, unsigned short* __restrict__ hT)
{
    __shared__ float Dp[4][2][16];
    __shared__ float Dscale[32];

    const int b = blockIdx.y;
    const int mtile0 = blockIdx.x << 5;
    const int tid = threadIdx.x;
    const int wv = tid >> 6, l = tid & 63, col = l & 31, hl = l >> 5;

    const bf16x8 Gf = *(const bf16x8*)(gb + (((size_t)(b * 4096 + mtile0 + col)) << 4) + (hl << 3));

    const f32x16 Z = {0.f, 0.f, 0.f, 0.f, 0.f, 0.f, 0.f, 0.f,
                      0.f, 0.f, 0.f, 0.f, 0.f, 0.f, 0.f, 0.f};
    float Dacc[16];
#pragma unroll
    for (int r = 0; r < 16; ++r) Dacc[r] = 0.f;

    const unsigned short* fbase = fb + (((size_t)(b * 4096 + (wv << 10))) << 4);

    for (int nc = 0; nc < 32; ++nc) {
        const unsigned short* fr = fbase + ((size_t)((nc << 5) + col) << 4);
        const bf16x8 Fhi = *(const bf16x8*)fr;
        const bf16x8 Flo = *(const bf16x8*)(fr + 8);
        f32x16 T = __builtin_amdgcn_mfma_f32_32x32x16_bf16(Gf, Fhi, Z, 0, 0, 0);
        T = __builtin_amdgcn_mfma_f32_32x32x16_bf16(Gf, Flo, T, 0, 0, 0);
#pragma unroll
        for (int r = 0; r < 16; ++r)
            Dacc[r] += __builtin_amdgcn_exp2f(T[r]);
    }

#pragma unroll
    for (int s = 1; s < 32; s <<= 1) {
#pragma unroll
        for (int r = 0; r < 16; ++r)
            Dacc[r] += __shfl_xor(Dacc[r], s);
    }

    if (col == 0) {
#pragma unroll
        for (int r = 0; r < 16; ++r) Dp[wv][hl][r] = Dacc[r];
    }
    __syncthreads();
    if (tid < 32) {
        const int r = tid & 15, h = tid >> 4;
        const float D = Dp[0][h][r] + Dp[1][h][r] + Dp[2][h][r] + Dp[3][h][r];
        const int m = (r & 3) + ((r >> 2) << 3) + (h << 2);
        Dscale[m] = 1.f / D;
    }
    __syncthreads();
    if (tid < 64) {
        const int ml = tid & 31, c0 = (tid >> 5) << 2;
        const float sc = Dscale[ml];
        const float4 hv = *(const float4*)(hb + (((size_t)(b * 4096 + mtile0 + ml)) << 3) + c0);
        unsigned short* o = hT + ((size_t)b << 15) + mtile0 + ml;
        o[(size_t)(c0    ) << 12] = f2bf(hv.x * sc);
        o[(size_t)(c0 + 1) << 12] = f2bf(hv.y * sc);
        o[(size_t)(c0 + 2) << 12] = f2bf(hv.z * sc);
        o[(size_t)(c0 + 3) << 12] = f2bf(hv.w * sc);
    }
}

// ---------------------------------------------------------------------------
// K4 pass2 (fused reduce): block = one 32-n tile; 4 waves split m (1024 each).
// Exact hi/lo QK; P -> bf16 via cvt_pk + shfl; O^T += mfma(hT, P).
// LDS-combine O across waves; write o[b][n][8] f32. grid (128, B), block 256.
// ---------------------------------------------------------------------------
__global__ __launch_bounds__(256) void pass2_k(
    const unsigned short* __restrict__ fb, const unsigned short* __restrict__ gb,
    const unsigned short* __restrict__ hT, float* __restrict__ o)
{
    __shared__ float red[4][64][4];

    const int b = blockIdx.y, nt = blockIdx.x;
    const int tid = threadIdx.x, wv = tid >> 6, l = tid & 63;
    const int col = l & 31;
    const bool lo = l < 32;
    const int hl8 = lo ? 0 : 8;

    const unsigned short* frow = fb + (((size_t)(b * 4096 + (nt << 5) + col)) << 4);
    const bf16x8 Fhi = *(const bf16x8*)frow;
    const bf16x8 Flo = *(const bf16x8*)(frow + 8);

    const f32x16 Z = {0.f, 0.f, 0.f, 0.f, 0.f, 0.f, 0.f, 0.f,
                      0.f, 0.f, 0.f, 0.f, 0.f, 0.f, 0.f, 0.f};
    f32x16 Oacc = Z;

    const unsigned short* hbase = hT + ((size_t)b << 15) + ((size_t)col << 12) + hl8;
    const bool hvalid = col < 8;

    for (int mci = 0; mci < 32; ++mci) {
        const int mc = (wv << 5) + mci;
        const bf16x8 Gf = *(const bf16x8*)(gb + (((size_t)(b * 4096 + (mc << 5) + col)) << 4) + hl8);
        f32x16 T = __builtin_amdgcn_mfma_f32_32x32x16_bf16(Gf, Fhi, Z, 0, 0, 0);
        T = __builtin_amdgcn_mfma_f32_32x32x16_bf16(Gf, Flo, T, 0, 0, 0);

        unsigned w[8];
#pragma unroll
        for (int pp = 0; pp < 8; ++pp)
            w[pp] = cvt_pk_bf16(__builtin_amdgcn_exp2f(T[2 * pp]),
                                __builtin_amdgcn_exp2f(T[2 * pp + 1]));

        const unsigned ea = __shfl_xor(lo ? w[2] : w[0], 32);
        const unsigned eb = __shfl_xor(lo ? w[3] : w[1], 32);
        const unsigned ec = __shfl_xor(lo ? w[6] : w[4], 32);
        const unsigned ed = __shfl_xor(lo ? w[7] : w[5], 32);

        union { unsigned u[4]; bf16x8 v; } B1, B2;
        B1.u[0] = lo ? w[0] : ea;  B1.u[1] = lo ? w[1] : eb;
        B1.u[2] = lo ? ea   : w[2]; B1.u[3] = lo ? eb   : w[3];
        B2.u[0] = lo ? w[4] : ec;  B2.u[1] = lo ? w[5] : ed;
        B2.u[2] = lo ? ec   : w[6]; B2.u[3] = lo ? ed   : w[7];

        bf16x8 A1 = {0, 0, 0, 0, 0, 0, 0, 0};
        bf16x8 A2 = {0, 0, 0, 0, 0, 0, 0, 0};
        if (hvalid) {
            A1 = *(const bf16x8*)(hbase + (mc << 5));
            A2 = *(const bf16x8*)(hbase + (mc << 5) + 16);
        }
        Oacc = __builtin_amdgcn_mfma_f32_32x32x16_bf16(A1, B1.v, Oacc, 0, 0, 0);
        Oacc = __builtin_amdgcn_mfma_f32_32x32x16_bf16(A2, B2.v, Oacc, 0, 0, 0);
    }

    *(float4*)&red[wv][l][0] = make_float4(Oacc[0], Oacc[1], Oacc[2], Oacc[3]);
    __syncthreads();
    if (tid < 64) {
        const float4 s0 = *(const float4*)&red[0][tid][0];
        const float4 s1 = *(const float4*)&red[1][tid][0];
        const float4 s2 = *(const float4*)&red[2][tid][0];
        const float4 s3 = *(const float4*)&red[3][tid][0];
        const float4 s = make_float4(s0.x + s1.x + s2.x + s3.x,
                                     s0.y + s1.y + s2.y + s3.y,
                                     s0.z + s1.z + s2.z + s3.z,
                                     s0.w + s1.w + s2.w + s3.w);
        float* op = o + (((size_t)(b * 4096 + (nt << 5) + (tid & 31))) << 3) + ((tid >> 5) << 2);
        *(float4*)op = s;
    }
}

// ---------------------------------------------------------------------------
// K5 post: i 1x1-conv (8->64) + bias + BN + residual; emits out2T as
// pixel-major bf16 (conv2's input format) via LDS transpose.
// grid (64, B), block 256 (64 pixels x 64 co per block).
// ---------------------------------------------------------------------------
__global__ __launch_bounds__(256) void post_k(
    const float* __restrict__ o, const float* __restrict__ out1,
    const float* __restrict__ i_w, const float* __restrict__ i_b,
    const float* __restrict__ i_bw, const float* __restrict__ i_bb,
    const float* __restrict__ i_bm, const float* __restrict__ i_bv,
    unsigned short* __restrict__ out2T)
{
    __shared__ float          os[64][12];
    __shared__ unsigned short ls[64][72];

    const int b = blockIdx.y, p0 = blockIdx.x << 6;
    const int tid = threadIdx.x;

    if (tid < 128) {
        const int pix = tid >> 1, hf = tid & 1;
        *(float4*)&os[pix][hf * 4] =
            *(const float4*)(o + (((size_t)(b * 4096 + p0 + pix)) << 3) + hf * 4);
    }
    __syncthreads();

    const int co = tid >> 2, pq = tid & 3;
    const float inv = i_bw[co] * rsqrtf(i_bv[co] + EPSBN);
    const float bs  = i_b[co] * inv + i_bb[co] - i_bm[co] * inv;
    float iw[8];
#pragma unroll
    for (int c = 0; c < 8; ++c) iw[c] = i_w[co * 8 + c] * inv;

    const float* o1p = out1 + (((size_t)(b * 64 + co)) << 12) + p0 + pq * 16;
#pragma unroll
    for (int k = 0; k < 16; ++k) {
        const int pix = pq * 16 + k;
        const float4 oa = *(const float4*)&os[pix][0];
        const float4 ob = *(const float4*)&os[pix][4];
        const float v = oa.x * iw[0] + oa.y * iw[1] + oa.z * iw[2] + oa.w * iw[3]
                      + ob.x * iw[4] + ob.y * iw[5] + ob.z * iw[6] + ob.w * iw[7];
        ls[pix][co] = f2bf(v + bs + o1p[k]);
    }
    __syncthreads();

    const int pix = tid >> 2, cg = tid & 3;
    const uint4 a  = *(const uint4*)&ls[pix][cg << 4];
    const uint4 b2 = *(const uint4*)&ls[pix][(cg << 4) + 8];
    unsigned short* dst = out2T + (((size_t)(b * 4096 + p0 + pix)) << 6) + (cg << 4);
    *(uint4*)dst       = a;
    *(uint4*)(dst + 8) = b2;
}

// ---------------------------------------------------------------------------
extern "C" void kernel_launch(void* const* d_in, const int* in_sizes, int n_in,
                              void* d_out, int out_size, void* d_ws, size_t ws_size,
                              hipStream_t stream) {
    const float* x       = (const float*)d_in[0];
    const float* conv1_w = (const float*)d_in[1];
    const float* conv2_w = (const float*)d_in[2];
    const float* f_w  = (const float*)d_in[3];
    const float* f_b  = (const float*)d_in[4];
    const float* f_bw = (const float*)d_in[5];
    const float* f_bb = (const float*)d_in[6];
    const float* f_bm = (const float*)d_in[7];
    const float* f_bv = (const float*)d_in[8];
    const float* g_w  = (const float*)d_in[9];
    const float* g_b  = (const float*)d_in[10];
    const float* g_bw = (const float*)d_in[11];
    const float* g_bb = (const float*)d_in[12];
    const float* g_bm = (const float*)d_in[13];
    const float* g_bv = (const float*)d_in[14];
    const float* gamma = (const float*)d_in[15];
    const float* h_w  = (const float*)d_in[16];
    const float* h_b  = (const float*)d_in[17];
    const float* h_bw = (const float*)d_in[18];
    const float* h_bb = (const float*)d_in[19];
    const float* h_bm = (const float*)d_in[20];
    const float* h_bv = (const float*)d_in[21];
    const float* i_w  = (const float*)d_in[22];
    const float* i_b  = (const float*)d_in[23];
    const float* i_bw = (const float*)d_in[24];
    const float* i_bb = (const float*)d_in[25];
    const float* i_bm = (const float*)d_in[26];
    const float* i_bv = (const float*)d_in[27];

    float* ws = (float*)d_ws;
    float* out1 = ws;                                          // 1,048,576 f
    unsigned short* xT    = (unsigned short*)(ws + 1048576);   //   524,288 f
    unsigned short* fbuf  = (unsigned short*)(ws + 1572864);   //   131,072 f
    unsigned short* gbuf  = (unsigned short*)(ws + 1703936);   //   131,072 f
    float* hbuf = ws + 1835008;                                //   131,072 f
    unsigned short* hT    = (unsigned short*)(ws + 1966080);   //    65,536 f
    unsigned short* wt1   = (unsigned short*)(ws + 2031616);   //    18,432 f
    unsigned short* wt2   = (unsigned short*)(ws + 2050048);   //    18,432 f
    unsigned short* out2T = (unsigned short*)(ws + 2068480);   //   524,288 f
    float* obuf = hbuf;   // hbuf dead after pass1_k

    // K0: x -> xT (bf16 pixel-major); weights -> wt1/wt2 (bf16 [t][co][ci])
    prep_k<<<292, 256, 0, stream>>>(x, conv1_w, conv2_w, xT, wt1, wt2);

    // K1: conv1 (MFMA) -> out1 (fp32 channel-major)
    conv3x3_k<<<dim3(64, 2, 4), 256, 0, stream>>>(xT, wt1, out1);

    // K2: projections -> f,g bf16 hi/lo (f has L2E), h f32
    proj_k<<<256, 256, 0, stream>>>(out1,
        f_w, f_b, f_bw, f_bb, f_bm, f_bv,
        g_w, g_b, g_bw, g_bb, g_bm, g_bv,
        h_w, h_b, h_bw, h_bb, h_bm, h_bv,
        gamma, fbuf, gbuf, hbuf);

    // K3: pass1 MFMA (fused D-reduce) -> hT = bf16(h / D) transposed
    pass1_k<<<dim3(128, 4), 256, 0, stream>>>(fbuf, gbuf, hbuf, hT);

    // K4: pass2 MFMA (fused O-reduce) -> obuf f32 [b][n][8]
    pass2_k<<<dim3(128, 4), 256, 0, stream>>>(fbuf, gbuf, hT, obuf);

    // K5: i-conv + BN + residual -> out2T (bf16 pixel-major)
    post_k<<<dim3(64, 4), 256, 0, stream>>>(obuf, out1,
        i_w, i_b, i_bw, i_bb, i_bm, i_bv, out2T);

    // K6: conv2 (MFMA) -> d_out
    conv3x3_k<<<dim3(64, 2, 4), 256, 0, stream>>>(out2T, wt2, (float*)d_out);
}